// Round 13
// baseline (1056.608 us; speedup 1.0000x reference)
//
#include <hip/hip_runtime.h>

// Problem constants
#define N_NODESC 50000
#define N_EDGESC 800000
#define EPSF 1e-5f
#define NTILE 782                   // ceil(50000/64)  (agg tiles)
#define NTBLK 1563                  // ceil(50000/32)  (k_T blocks)
#define NKEYS 800000                // 50000*16 (dst,combo) keys
#define NHBLK 3125                  // NKEYS/256
#define NEBLK 3125                  // 800000/256

typedef __attribute__((ext_vector_type(8))) short short8;
typedef __attribute__((ext_vector_type(16))) float f32x16;
typedef __attribute__((ext_vector_type(4))) float f32x4;

// ---- ws layout (bytes), total ~256.7 MB ----
#define WS_SCALE 0
#define WS_SHIFT 256
#define WS_BSUM  512                  // 3125 int
#define WS_PBUF  13056                // 782*128 f32 -> ends 413440
#define WS_HIST  413440               // 800000 int
#define WS_FILL  3613440              // 800000 int (contiguous after hist)
#define WS_SEG   6813440              // 800001 int
#define WS_ELIST 10013504             // 800000 int (tidx = src*16+c)
#define WS_AHI   13213504             // 128 KB
#define WS_ALO   13344576             // 128 KB
#define WS_HHI   13475648             // 50016*64 ushort (padded rows)
#define WS_HLO   19877696             // 50016*64 ushort
#define WS_HB    26279744             // 50000*64 f32
#define WS_OUTB  39079744             // 50000*64 f32
#define WS_T     51879744             // 50016*1024 f32 = 204.9 MB

// key = (dst, combo)
__device__ __forceinline__ int edge_key(int d, int c) {
    return d * 16 + c;
}

// ---------------- histogram ----------------
__global__ __launch_bounds__(256)
void k_hist(const int* __restrict__ src, const int* __restrict__ dst,
            const int* __restrict__ labels, const int* __restrict__ bidx,
            int* __restrict__ hist)
{
    const int e = blockIdx.x * 256 + threadIdx.x;
    if (e >= N_EDGESC) return;
    const int s = src[e], d = dst[e];
    const int c = (labels[d] * 2 + labels[s]) * 4 + bidx[e];
    atomicAdd(&hist[edge_key(d, c)], 1);
}

// ---------------- 3-level scan ----------------
__global__ __launch_bounds__(256)
void k_bsum(const int* __restrict__ hist, int* __restrict__ bsum)
{
    __shared__ int s[256];
    const int i = blockIdx.x * 256 + threadIdx.x;
    s[threadIdx.x] = hist[i];
    __syncthreads();
    for (int off = 128; off > 0; off >>= 1) {
        if (threadIdx.x < off) s[threadIdx.x] += s[threadIdx.x + off];
        __syncthreads();
    }
    if (threadIdx.x == 0) bsum[blockIdx.x] = s[0];
}

__global__ __launch_bounds__(1024)
void k_bscan2(int* __restrict__ bsum)   // in-place exclusive scan of NHBLK entries
{
    __shared__ int s[1024];
    const int t = threadIdx.x;
    int v[4]; int tot = 0;
#pragma unroll
    for (int j = 0; j < 4; ++j) {
        const int i = t * 4 + j;
        v[j] = (i < NHBLK) ? bsum[i] : 0;
        tot += v[j];
    }
    s[t] = tot; __syncthreads();
    for (int off = 1; off < 1024; off <<= 1) {
        const int x = (t >= off) ? s[t - off] : 0;
        __syncthreads();
        s[t] += x;
        __syncthreads();
    }
    int base = s[t] - tot;
#pragma unroll
    for (int j = 0; j < 4; ++j) {
        const int i = t * 4 + j;
        if (i < NHBLK) bsum[i] = base;
        base += v[j];
    }
}

__global__ __launch_bounds__(256)
void k_escan2(const int* __restrict__ hist, const int* __restrict__ bsum,
              int* __restrict__ seg)
{
    __shared__ int s[256];
    const int t = threadIdx.x;
    const int i = blockIdx.x * 256 + t;
    const int v = hist[i];
    s[t] = v; __syncthreads();
    for (int off = 1; off < 256; off <<= 1) {
        const int x = (t >= off) ? s[t - off] : 0;
        __syncthreads();
        s[t] += x;
        __syncthreads();
    }
    const int incl = s[t];
    seg[i] = bsum[blockIdx.x] + incl - v;
    if (i == NKEYS - 1) seg[NKEYS] = bsum[blockIdx.x] + incl;
}

__global__ __launch_bounds__(256)
void k_scat(const int* __restrict__ src, const int* __restrict__ dst,
            const int* __restrict__ labels, const int* __restrict__ bidx,
            const int* __restrict__ seg, int* __restrict__ fill,
            int* __restrict__ elist)
{
    const int e = blockIdx.x * 256 + threadIdx.x;
    if (e >= N_EDGESC) return;
    const int s = src[e], d = dst[e];
    const int c = (labels[d] * 2 + labels[s]) * 4 + bidx[e];
    const int k = edge_key(d, c);
    const int pos = seg[k] + atomicAdd(&fill[k], 1);
    elist[pos] = s * 16 + c;               // tidx into T
}

// ---- MFMA A-fragments (split bf16 hi/lo), layout verified R5/R8 ----
__global__ void k_mfrag(const float* __restrict__ M, ushort* __restrict__ Ahi,
                        ushort* __restrict__ Alo)
{
    const int c = blockIdx.x;
    for (int slot = threadIdx.x; slot < 512; slot += 256) {
        const int t = slot >> 8, s = (slot >> 6) & 3, lane = slot & 63;
        const int row = (lane & 31) + 32 * t;
        const int kb = 16 * s + 8 * (lane >> 5);
        const int fid = ((c * 2 + t) * 4 + s) * 64 + lane;
#pragma unroll
        for (int j = 0; j < 8; ++j) {
            const float v = M[c * 4096 + row * 64 + kb + j];
            const unsigned b = __float_as_uint(v);
            const float lof = v - __uint_as_float(b & 0xFFFF0000u);
            Ahi[fid * 8 + j] = (ushort)(b >> 16);
            Alo[fid * 8 + j] = (ushort)(__float_as_uint(lof) >> 16);
        }
    }
}

// ---------------- h = in @ W + b, + split-bf16 outputs ----------------
__global__ __launch_bounds__(256)
void k_h(const float* __restrict__ in, const float* __restrict__ W,
         const float* __restrict__ b, float* __restrict__ h,
         ushort* __restrict__ hhi, ushort* __restrict__ hlo, const int F)
{
    const int t = blockIdx.x * 256 + threadIdx.x;
    if (t >= N_NODESC * 64) return;
    const int n = t >> 6, e = t & 63;
    const float* __restrict__ xr = in + (long)n * F;
    float acc = b[e];
    for (int f = 0; f < F; f += 4) {
        acc += xr[f]     * W[f * 64 + e];
        acc += xr[f + 1] * W[(f + 1) * 64 + e];
        acc += xr[f + 2] * W[(f + 2) * 64 + e];
        acc += xr[f + 3] * W[(f + 3) * 64 + e];
    }
    h[t] = acc;
    const unsigned bb = __float_as_uint(acc);
    const float lof = acc - __uint_as_float(bb & 0xFFFF0000u);
    hhi[t] = (ushort)(bb >> 16);
    hlo[t] = (ushort)(__float_as_uint(lof) >> 16);
}

// ---------------- fused LN-apply + relu + next-layer GEMM + split -----------
__global__ __launch_bounds__(256)
void k_happly(const float* __restrict__ outb, const float* __restrict__ scale,
              const float* __restrict__ shift, const float* __restrict__ W,
              const float* __restrict__ b, float* __restrict__ h,
              ushort* __restrict__ hhi, ushort* __restrict__ hlo)
{
    __shared__ float act[4][64];
    const int nl = threadIdx.x >> 6, o = threadIdx.x & 63;
    const int n = blockIdx.x * 4 + nl;
    const float v = outb[(long)n * 64 + o] * scale[o] + shift[o];
    act[nl][o] = fmaxf(v, 0.f);
    __syncthreads();
    float a = b[o];
#pragma unroll 16
    for (int f = 0; f < 64; ++f) a += act[nl][f] * W[f * 64 + o];
    const long t = (long)n * 64 + o;
    h[t] = a;
    const unsigned bb = __float_as_uint(a);
    const float lof = a - __uint_as_float(bb & 0xFFFF0000u);
    hhi[t] = (ushort)(bb >> 16);
    hlo[t] = (ushort)(__float_as_uint(lof) >> 16);
}

// ---------------- dense transform table: T[n][c*64+o] = (M_c h_n)[o] --------
// Block = 32 nodes; wave w handles combos w, w+4, w+8, w+12. B-frags are
// SEQUENTIAL rows of hhi/hlo (no gather). MFMA math identical to R8.
__global__ __launch_bounds__(256, 3)
void k_T(const ushort* __restrict__ hhi, const ushort* __restrict__ hlo,
         const ushort* __restrict__ Ahi, const ushort* __restrict__ Alo,
         float* __restrict__ T)
{
    const int lane = threadIdx.x & 63, w = threadIdx.x >> 6;
    const int col = lane & 31, hig = lane >> 5;
    const int node = blockIdx.x * 32 + col;

    const ushort* __restrict__ rh = hhi + (long)node * 64 + hig * 8;
    const ushort* __restrict__ rl = hlo + (long)node * 64 + hig * 8;
    short8 bh[4], bl[4];
#pragma unroll
    for (int s = 0; s < 4; ++s) {
        bh[s] = *(const short8*)&rh[s * 16];
        bl[s] = *(const short8*)&rl[s * 16];
    }
    const bool wr = node < N_NODESC;
    float* __restrict__ Trow = T + (long)node * 1024;

    for (int ci = 0; ci < 4; ++ci) {
        const int c = w + 4 * ci;
        f32x16 c0, c1;
#pragma unroll
        for (int i = 0; i < 16; ++i) { c0[i] = 0.f; c1[i] = 0.f; }
#pragma unroll
        for (int s = 0; s < 4; ++s) {
            const int fidb = (c * 8 + s) * 64 + lane;
            const short8 a0h = *(const short8*)&Ahi[fidb * 8];
            const short8 a1h = *(const short8*)&Ahi[(fidb + 256) * 8];
            const short8 a0l = *(const short8*)&Alo[fidb * 8];
            const short8 a1l = *(const short8*)&Alo[(fidb + 256) * 8];
            c0 = __builtin_amdgcn_mfma_f32_32x32x16_bf16(a0h, bh[s], c0, 0, 0, 0);
            c1 = __builtin_amdgcn_mfma_f32_32x32x16_bf16(a1h, bh[s], c1, 0, 0, 0);
            c0 = __builtin_amdgcn_mfma_f32_32x32x16_bf16(a0h, bl[s], c0, 0, 0, 0);
            c1 = __builtin_amdgcn_mfma_f32_32x32x16_bf16(a1h, bl[s], c1, 0, 0, 0);
            c0 = __builtin_amdgcn_mfma_f32_32x32x16_bf16(a0l, bh[s], c0, 0, 0, 0);
            c1 = __builtin_amdgcn_mfma_f32_32x32x16_bf16(a1l, bh[s], c1, 0, 0, 0);
        }
        if (wr) {
#pragma unroll
            for (int rq = 0; rq < 4; ++rq) {
                const int fb = 8 * rq + 4 * hig;   // C row = (r&3)+8(r>>2)+4hig
                f32x4 v0 = {c0[4*rq], c0[4*rq+1], c0[4*rq+2], c0[4*rq+3]};
                f32x4 v1 = {c1[4*rq], c1[4*rq+1], c1[4*rq+2], c1[4*rq+3]};
                __builtin_nontemporal_store(v0, (f32x4*)&Trow[c * 64 + fb]);
                __builtin_nontemporal_store(v1, (f32x4*)&Trow[c * 64 + fb + 32]);
            }
        }
    }
}

// ---------------- streaming gather-aggregate + residual + LN partials -------
// Block = 64-dst tile; wave w owns dsts [16w,16w+16); lane = (dl, fq).
// Each dl-group (4 lanes) sums its dst's T rows (2-edge unrolled for MLP).
__global__ __launch_bounds__(256, 4)
void k_agg2(const float* __restrict__ T, const float* __restrict__ hres,
            const int* __restrict__ elist, const int* __restrict__ seg,
            float* __restrict__ outb, float* __restrict__ pbuf)
{
    __shared__ float red[2][4][64];
    const int tid = threadIdx.x;
    const int w = tid >> 6, lane = tid & 63;
    const int dl = lane >> 2, fq = lane & 3;
    const int tile = blockIdx.x;
    const int gd = tile * 64 + w * 16 + dl;

    float4 a0 = {0,0,0,0}, a1 = a0, a2 = a0, a3 = a0;
    float4 b0 = a0, b1 = a0, b2 = a0, b3 = a0;

    if (gd < N_NODESC) {
        const int p0 = seg[gd * 16];
        const int p1 = seg[gd * 16 + 16];
        const float* __restrict__ Tf = T + 16 * fq;
        int p = p0;
        for (; p + 2 <= p1; p += 2) {
            const long t0 = (long)elist[p] * 64;
            const long t1 = (long)elist[p + 1] * 64;
            const float4 u0 = *(const float4*)&Tf[t0 + 0];
            const float4 u1 = *(const float4*)&Tf[t0 + 4];
            const float4 u2 = *(const float4*)&Tf[t0 + 8];
            const float4 u3 = *(const float4*)&Tf[t0 + 12];
            const float4 x0 = *(const float4*)&Tf[t1 + 0];
            const float4 x1 = *(const float4*)&Tf[t1 + 4];
            const float4 x2 = *(const float4*)&Tf[t1 + 8];
            const float4 x3 = *(const float4*)&Tf[t1 + 12];
            a0.x += u0.x; a0.y += u0.y; a0.z += u0.z; a0.w += u0.w;
            a1.x += u1.x; a1.y += u1.y; a1.z += u1.z; a1.w += u1.w;
            a2.x += u2.x; a2.y += u2.y; a2.z += u2.z; a2.w += u2.w;
            a3.x += u3.x; a3.y += u3.y; a3.z += u3.z; a3.w += u3.w;
            b0.x += x0.x; b0.y += x0.y; b0.z += x0.z; b0.w += x0.w;
            b1.x += x1.x; b1.y += x1.y; b1.z += x1.z; b1.w += x1.w;
            b2.x += x2.x; b2.y += x2.y; b2.z += x2.z; b2.w += x2.w;
            b3.x += x3.x; b3.y += x3.y; b3.z += x3.z; b3.w += x3.w;
        }
        if (p < p1) {
            const long t0 = (long)elist[p] * 64;
            const float4 u0 = *(const float4*)&Tf[t0 + 0];
            const float4 u1 = *(const float4*)&Tf[t0 + 4];
            const float4 u2 = *(const float4*)&Tf[t0 + 8];
            const float4 u3 = *(const float4*)&Tf[t0 + 12];
            a0.x += u0.x; a0.y += u0.y; a0.z += u0.z; a0.w += u0.w;
            a1.x += u1.x; a1.y += u1.y; a1.z += u1.z; a1.w += u1.w;
            a2.x += u2.x; a2.y += u2.y; a2.z += u2.z; a2.w += u2.w;
            a3.x += u3.x; a3.y += u3.y; a3.z += u3.z; a3.w += u3.w;
        }
        a0.x += b0.x; a0.y += b0.y; a0.z += b0.z; a0.w += b0.w;
        a1.x += b1.x; a1.y += b1.y; a1.z += b1.z; a1.w += b1.w;
        a2.x += b2.x; a2.y += b2.y; a2.z += b2.z; a2.w += b2.w;
        a3.x += b3.x; a3.y += b3.y; a3.z += b3.z; a3.w += b3.w;
    }

    // ---- epilogue (R8 verbatim): residual + store + LN partials ----
    float4 v[4] = {a0, a1, a2, a3};
    if (gd < N_NODESC) {
        const float4* __restrict__ hr = (const float4*)(hres + (long)gd * 64 + 16 * fq);
        float4* __restrict__ ob = (float4*)(outb + (long)gd * 64 + 16 * fq);
#pragma unroll
        for (int u = 0; u < 4; ++u) {
            const float4 r = hr[u];
            v[u].x += r.x; v[u].y += r.y; v[u].z += r.z; v[u].w += r.w;
            ob[u] = v[u];
        }
    } else {
#pragma unroll
        for (int u = 0; u < 4; ++u) v[u] = make_float4(0.f, 0.f, 0.f, 0.f);
    }
    float s1[16], s2[16];
#pragma unroll
    for (int u = 0; u < 4; ++u) {
        s1[4*u+0] = v[u].x; s2[4*u+0] = v[u].x * v[u].x;
        s1[4*u+1] = v[u].y; s2[4*u+1] = v[u].y * v[u].y;
        s1[4*u+2] = v[u].z; s2[4*u+2] = v[u].z * v[u].z;
        s1[4*u+3] = v[u].w; s2[4*u+3] = v[u].w * v[u].w;
    }
#pragma unroll
    for (int j = 0; j < 16; ++j) {
        s1[j] += __shfl_xor(s1[j], 4);  s2[j] += __shfl_xor(s2[j], 4);
        s1[j] += __shfl_xor(s1[j], 8);  s2[j] += __shfl_xor(s2[j], 8);
        s1[j] += __shfl_xor(s1[j], 16); s2[j] += __shfl_xor(s2[j], 16);
        s1[j] += __shfl_xor(s1[j], 32); s2[j] += __shfl_xor(s2[j], 32);
    }
    if (dl == 0) {
#pragma unroll
        for (int j = 0; j < 16; ++j) {
            red[0][w][16 * fq + j] = s1[j];
            red[1][w][16 * fq + j] = s2[j];
        }
    }
    __syncthreads();
    if (tid < 64) {
        const float t1 = red[0][0][tid] + red[0][1][tid] + red[0][2][tid] + red[0][3][tid];
        const float t2 = red[1][0][tid] + red[1][1][tid] + red[1][2][tid] + red[1][3][tid];
        pbuf[tile * 128 + tid] = t1;
        pbuf[tile * 128 + 64 + tid] = t2;
    }
}

// ---------------- reduce LN partials -> scale/shift ----------------
__global__ __launch_bounds__(1024)
void k_norm2(const float* __restrict__ pbuf, const float* __restrict__ g,
             const float* __restrict__ be, float* __restrict__ scale,
             float* __restrict__ shift)
{
    __shared__ float s[1024];
    const int t = threadIdx.x, j = t & 127, gg = t >> 7;
    float a = 0.f;
    for (int b = gg; b < NTILE; b += 8) a += pbuf[b * 128 + j];
    s[t] = a;
    __syncthreads();
    if (t < 128) {
        float tot = 0.f;
#pragma unroll
        for (int k = 0; k < 8; ++k) tot += s[j + 128 * k];
        s[t] = tot;
    }
    __syncthreads();
    if (t < 64) {
        const double mu  = (double)s[t] / (double)N_NODESC;
        const double var = (double)s[64 + t] / (double)N_NODESC - mu * mu;
        const double sc  = (double)g[t] / sqrt(var + (double)EPSF);
        scale[t] = (float)sc;
        shift[t] = (float)((double)be[t] - mu * sc);
    }
}

// ---------------- final projection (LN apply fused) ----------------
__global__ __launch_bounds__(256)
void k_out(const float* __restrict__ outb, const float* __restrict__ scale,
           const float* __restrict__ shift, const float* __restrict__ resW,
           const float* __restrict__ resb, float* __restrict__ out)
{
    const int n = blockIdx.x * 256 + threadIdx.x;
    if (n >= N_NODESC) return;
    float a0 = resb[0], a1 = resb[1];
    const float* __restrict__ r = outb + (long)n * 64;
#pragma unroll 8
    for (int e = 0; e < 64; ++e) {
        const float v = fmaxf(r[e] * scale[e] + shift[e], 0.f);
        a0 += v * resW[2 * e];
        a1 += v * resW[2 * e + 1];
    }
    out[2 * n] = a0;
    out[2 * n + 1] = a1;
}

extern "C" void kernel_launch(void* const* d_in, const int* in_sizes, int n_in,
                              void* d_out, int out_size, void* d_ws, size_t ws_size,
                              hipStream_t stream)
{
    const float* x      = (const float*)d_in[0];
    const float* M      = (const float*)d_in[1];
    const int*   src    = (const int*)d_in[2];
    const int*   dst    = (const int*)d_in[3];
    const int*   labels = (const int*)d_in[4];
    const int*   bidx   = (const int*)d_in[5];
    const float* resW   = (const float*)d_in[18];
    const float* resb   = (const float*)d_in[19];
    float* out = (float*)d_out;

    char* ws = (char*)d_ws;
    float*  scale = (float*)(ws + WS_SCALE);
    float*  shift = (float*)(ws + WS_SHIFT);
    int*    bsum  = (int*)(ws + WS_BSUM);
    float*  pbuf  = (float*)(ws + WS_PBUF);
    int*    hist  = (int*)(ws + WS_HIST);
    int*    fill  = (int*)(ws + WS_FILL);
    int*    seg   = (int*)(ws + WS_SEG);
    int*    elist = (int*)(ws + WS_ELIST);
    ushort* Ahi   = (ushort*)(ws + WS_AHI);
    ushort* Alo   = (ushort*)(ws + WS_ALO);
    ushort* hhi   = (ushort*)(ws + WS_HHI);
    ushort* hlo   = (ushort*)(ws + WS_HLO);
    float*  hB    = (float*)(ws + WS_HB);
    float*  outb  = (float*)(ws + WS_OUTB);
    float*  T     = (float*)(ws + WS_T);

    const int NB64 = (N_NODESC * 64 + 255) / 256;  // 12500

    // ---- preprocessing (graph + M constant across layers) ----
    hipMemsetAsync(hist, 0, 2 * (size_t)NKEYS * sizeof(int), stream);  // hist + fill
    k_hist<<<NEBLK, 256, 0, stream>>>(src, dst, labels, bidx, hist);
    k_bsum<<<NHBLK, 256, 0, stream>>>(hist, bsum);
    k_bscan2<<<1, 1024, 0, stream>>>(bsum);
    k_escan2<<<NHBLK, 256, 0, stream>>>(hist, bsum, seg);
    k_scat<<<NEBLK, 256, 0, stream>>>(src, dst, labels, bidx, seg, fill, elist);
    k_mfrag<<<16, 256, 0, stream>>>(M, Ahi, Alo);

    for (int l = 0; l < 3; ++l) {
        const float* W  = (const float*)d_in[6 + 4 * l];
        const float* b  = (const float*)d_in[7 + 4 * l];
        const float* g  = (const float*)d_in[8 + 4 * l];
        const float* be = (const float*)d_in[9 + 4 * l];

        if (l == 0) {
            k_h<<<NB64, 256, 0, stream>>>(x, W, b, hB, hhi, hlo, 128);
        } else {
            k_happly<<<N_NODESC / 4, 256, 0, stream>>>(outb, scale, shift, W, b,
                                                       hB, hhi, hlo);
        }
        k_T<<<NTBLK, 256, 0, stream>>>(hhi, hlo, Ahi, Alo, T);
        k_agg2<<<NTILE, 256, 0, stream>>>(T, hB, elist, seg, outb, pbuf);
        k_norm2<<<1, 1024, 0, stream>>>(pbuf, g, be, scale, shift);
    }
    k_out<<<(N_NODESC + 255) / 256, 256, 0, stream>>>(outb, scale, shift, resW, resb, out);
    (void)in_sizes; (void)n_in; (void)out_size; (void)ws_size;
}

// Round 14
// 903.723 us; speedup vs baseline: 1.1692x; 1.1692x over previous
//
#include <hip/hip_runtime.h>

// Problem constants
#define N_NODESC 50000
#define N_EDGESC 800000
#define EPSF 1e-5f
#define NTILE 782                   // ceil(50000/64)  (agg tiles)
#define NTBLK 1563                  // ceil(50000/32)  (k_T blocks)
#define NKEYS 800000                // 50000*16 (dst,combo) keys
#define NHBLK 3125                  // NKEYS/256
#define NEBLK 3125                  // 800000/256

typedef __attribute__((ext_vector_type(8))) short short8;
typedef __attribute__((ext_vector_type(16))) float f32x16;
typedef __attribute__((ext_vector_type(4))) float f32x4;

// ---- ws layout (bytes), total ~256.7 MB ----
#define WS_SCALE 0
#define WS_SHIFT 256
#define WS_BSUM  512                  // 3125 int
#define WS_PBUF  13056                // 782*128 f32 -> ends 413440
#define WS_HIST  413440               // 800000 int
#define WS_FILL  3613440              // 800000 int (contiguous after hist)
#define WS_SEG   6813440              // 800001 int
#define WS_ELIST 10013504             // 800000 int (tidx = src*16+c)
#define WS_AHI   13213504             // 128 KB
#define WS_ALO   13344576             // 128 KB
#define WS_HHI   13475648             // 50016*64 ushort (padded rows)
#define WS_HLO   19877696             // 50016*64 ushort
#define WS_HB    26279744             // 50000*64 f32
#define WS_OUTB  39079744             // 50000*64 f32
#define WS_T     51879744             // 50016*1024 f32 = 204.9 MB

// key = (dst, combo)
__device__ __forceinline__ int edge_key(int d, int c) {
    return d * 16 + c;
}

__device__ __forceinline__ float4 ntld(const float* p) {
    const f32x4 v = __builtin_nontemporal_load((const f32x4*)p);
    return make_float4(v[0], v[1], v[2], v[3]);
}

// ---------------- histogram ----------------
__global__ __launch_bounds__(256)
void k_hist(const int* __restrict__ src, const int* __restrict__ dst,
            const int* __restrict__ labels, const int* __restrict__ bidx,
            int* __restrict__ hist)
{
    const int e = blockIdx.x * 256 + threadIdx.x;
    if (e >= N_EDGESC) return;
    const int s = src[e], d = dst[e];
    const int c = (labels[d] * 2 + labels[s]) * 4 + bidx[e];
    atomicAdd(&hist[edge_key(d, c)], 1);
}

// ---------------- 3-level scan ----------------
__global__ __launch_bounds__(256)
void k_bsum(const int* __restrict__ hist, int* __restrict__ bsum)
{
    __shared__ int s[256];
    const int i = blockIdx.x * 256 + threadIdx.x;
    s[threadIdx.x] = hist[i];
    __syncthreads();
    for (int off = 128; off > 0; off >>= 1) {
        if (threadIdx.x < off) s[threadIdx.x] += s[threadIdx.x + off];
        __syncthreads();
    }
    if (threadIdx.x == 0) bsum[blockIdx.x] = s[0];
}

__global__ __launch_bounds__(1024)
void k_bscan2(int* __restrict__ bsum)   // in-place exclusive scan of NHBLK entries
{
    __shared__ int s[1024];
    const int t = threadIdx.x;
    int v[4]; int tot = 0;
#pragma unroll
    for (int j = 0; j < 4; ++j) {
        const int i = t * 4 + j;
        v[j] = (i < NHBLK) ? bsum[i] : 0;
        tot += v[j];
    }
    s[t] = tot; __syncthreads();
    for (int off = 1; off < 1024; off <<= 1) {
        const int x = (t >= off) ? s[t - off] : 0;
        __syncthreads();
        s[t] += x;
        __syncthreads();
    }
    int base = s[t] - tot;
#pragma unroll
    for (int j = 0; j < 4; ++j) {
        const int i = t * 4 + j;
        if (i < NHBLK) bsum[i] = base;
        base += v[j];
    }
}

__global__ __launch_bounds__(256)
void k_escan2(const int* __restrict__ hist, const int* __restrict__ bsum,
              int* __restrict__ seg)
{
    __shared__ int s[256];
    const int t = threadIdx.x;
    const int i = blockIdx.x * 256 + t;
    const int v = hist[i];
    s[t] = v; __syncthreads();
    for (int off = 1; off < 256; off <<= 1) {
        const int x = (t >= off) ? s[t - off] : 0;
        __syncthreads();
        s[t] += x;
        __syncthreads();
    }
    const int incl = s[t];
    seg[i] = bsum[blockIdx.x] + incl - v;
    if (i == NKEYS - 1) seg[NKEYS] = bsum[blockIdx.x] + incl;
}

__global__ __launch_bounds__(256)
void k_scat(const int* __restrict__ src, const int* __restrict__ dst,
            const int* __restrict__ labels, const int* __restrict__ bidx,
            const int* __restrict__ seg, int* __restrict__ fill,
            int* __restrict__ elist)
{
    const int e = blockIdx.x * 256 + threadIdx.x;
    if (e >= N_EDGESC) return;
    const int s = src[e], d = dst[e];
    const int c = (labels[d] * 2 + labels[s]) * 4 + bidx[e];
    const int k = edge_key(d, c);
    const int pos = seg[k] + atomicAdd(&fill[k], 1);
    elist[pos] = s * 16 + c;               // tidx into T
}

// ---- MFMA A-fragments (split bf16 hi/lo), layout verified R5/R8 ----
__global__ void k_mfrag(const float* __restrict__ M, ushort* __restrict__ Ahi,
                        ushort* __restrict__ Alo)
{
    const int c = blockIdx.x;
    for (int slot = threadIdx.x; slot < 512; slot += 256) {
        const int t = slot >> 8, s = (slot >> 6) & 3, lane = slot & 63;
        const int row = (lane & 31) + 32 * t;
        const int kb = 16 * s + 8 * (lane >> 5);
        const int fid = ((c * 2 + t) * 4 + s) * 64 + lane;
#pragma unroll
        for (int j = 0; j < 8; ++j) {
            const float v = M[c * 4096 + row * 64 + kb + j];
            const unsigned b = __float_as_uint(v);
            const float lof = v - __uint_as_float(b & 0xFFFF0000u);
            Ahi[fid * 8 + j] = (ushort)(b >> 16);
            Alo[fid * 8 + j] = (ushort)(__float_as_uint(lof) >> 16);
        }
    }
}

// ---------------- h = in @ W + b, + split-bf16 outputs ----------------
__global__ __launch_bounds__(256)
void k_h(const float* __restrict__ in, const float* __restrict__ W,
         const float* __restrict__ b, float* __restrict__ h,
         ushort* __restrict__ hhi, ushort* __restrict__ hlo, const int F)
{
    const int t = blockIdx.x * 256 + threadIdx.x;
    if (t >= N_NODESC * 64) return;
    const int n = t >> 6, e = t & 63;
    const float* __restrict__ xr = in + (long)n * F;
    float acc = b[e];
    for (int f = 0; f < F; f += 4) {
        acc += xr[f]     * W[f * 64 + e];
        acc += xr[f + 1] * W[(f + 1) * 64 + e];
        acc += xr[f + 2] * W[(f + 2) * 64 + e];
        acc += xr[f + 3] * W[(f + 3) * 64 + e];
    }
    h[t] = acc;
    const unsigned bb = __float_as_uint(acc);
    const float lof = acc - __uint_as_float(bb & 0xFFFF0000u);
    hhi[t] = (ushort)(bb >> 16);
    hlo[t] = (ushort)(__float_as_uint(lof) >> 16);
}

// ---------------- fused LN-apply + relu + next-layer GEMM + split -----------
__global__ __launch_bounds__(256)
void k_happly(const float* __restrict__ outb, const float* __restrict__ scale,
              const float* __restrict__ shift, const float* __restrict__ W,
              const float* __restrict__ b, float* __restrict__ h,
              ushort* __restrict__ hhi, ushort* __restrict__ hlo)
{
    __shared__ float act[4][64];
    const int nl = threadIdx.x >> 6, o = threadIdx.x & 63;
    const int n = blockIdx.x * 4 + nl;
    const float v = outb[(long)n * 64 + o] * scale[o] + shift[o];
    act[nl][o] = fmaxf(v, 0.f);
    __syncthreads();
    float a = b[o];
#pragma unroll 16
    for (int f = 0; f < 64; ++f) a += act[nl][f] * W[f * 64 + o];
    const long t = (long)n * 64 + o;
    h[t] = a;
    const unsigned bb = __float_as_uint(a);
    const float lof = a - __uint_as_float(bb & 0xFFFF0000u);
    hhi[t] = (ushort)(bb >> 16);
    hlo[t] = (ushort)(__float_as_uint(lof) >> 16);
}

// ---------------- dense transform table: T[n][c*64+o] = (M_c h_n)[o] --------
// Block = 32 nodes; wave w handles combos w, w+4, w+8, w+12. B-frags from
// SEQUENTIAL hhi/hlo rows (no gather). C-fragments staged through the R8
// LDS swizzle, then stored COALESCED (16 lanes = one 256B node-row chunk).
__global__ __launch_bounds__(256, 3)
void k_T(const ushort* __restrict__ hhi, const ushort* __restrict__ hlo,
         const ushort* __restrict__ Ahi, const ushort* __restrict__ Alo,
         float* __restrict__ T)
{
    __shared__ float msg[4][2048];        // per-wave 32 nodes x 64 feats (32 KB)
    const int tid = threadIdx.x;
    const int w = tid >> 6, lane = tid & 63;
    const int col = lane & 31, hig = lane >> 5;
    const int node = blockIdx.x * 32 + col;

    const ushort* __restrict__ rh = hhi + (long)node * 64 + hig * 8;
    const ushort* __restrict__ rl = hlo + (long)node * 64 + hig * 8;
    short8 bh[4], bl[4];
#pragma unroll
    for (int s = 0; s < 4; ++s) {
        bh[s] = *(const short8*)&rh[s * 16];
        bl[s] = *(const short8*)&rl[s * 16];
    }
    float* __restrict__ msgw = msg[w];
    float* __restrict__ Tb = T + (long)blockIdx.x * 32768;    // 32 rows x 1024

    for (int ci = 0; ci < 4; ++ci) {
        const int c = w + 4 * ci;
        f32x16 c0, c1;
#pragma unroll
        for (int i = 0; i < 16; ++i) { c0[i] = 0.f; c1[i] = 0.f; }
#pragma unroll
        for (int s = 0; s < 4; ++s) {
            const int fidb = (c * 8 + s) * 64 + lane;
            const short8 a0h = *(const short8*)&Ahi[fidb * 8];
            const short8 a1h = *(const short8*)&Ahi[(fidb + 256) * 8];
            const short8 a0l = *(const short8*)&Alo[fidb * 8];
            const short8 a1l = *(const short8*)&Alo[(fidb + 256) * 8];
            c0 = __builtin_amdgcn_mfma_f32_32x32x16_bf16(a0h, bh[s], c0, 0, 0, 0);
            c1 = __builtin_amdgcn_mfma_f32_32x32x16_bf16(a1h, bh[s], c1, 0, 0, 0);
            c0 = __builtin_amdgcn_mfma_f32_32x32x16_bf16(a0h, bl[s], c0, 0, 0, 0);
            c1 = __builtin_amdgcn_mfma_f32_32x32x16_bf16(a1h, bl[s], c1, 0, 0, 0);
            c0 = __builtin_amdgcn_mfma_f32_32x32x16_bf16(a0l, bh[s], c0, 0, 0, 0);
            c1 = __builtin_amdgcn_mfma_f32_32x32x16_bf16(a1l, bh[s], c1, 0, 0, 0);
        }

        // stage C tile to LDS: msg[col][feat], feat XOR-swizzled (R8 pattern)
        const int sw = (col & 7) << 3;
        const int cb = col * 64;
#pragma unroll
        for (int rq = 0; rq < 4; ++rq) {
            const int fb = 8 * rq + 4 * hig;       // C row = (r&3)+8(r>>2)+4hig
            float4 v0 = {c0[4*rq], c0[4*rq+1], c0[4*rq+2], c0[4*rq+3]};
            float4 v1 = {c1[4*rq], c1[4*rq+1], c1[4*rq+2], c1[4*rq+3]};
            *(float4*)&msgw[cb + (fb ^ sw)] = v0;
            *(float4*)&msgw[cb + ((fb + 32) ^ sw)] = v1;
        }
        asm volatile("s_waitcnt lgkmcnt(0)" ::: "memory");

        // coalesced store-out: lanes 0-15 -> one node-row's 256B chunk
#pragma unroll
        for (int i = 0; i < 8; ++i) {
            const int idx = i * 64 + lane;
            const int row = idx >> 4, quad = idx & 15;
            const int qs = (row & 7) << 3;
            const float4 vv = *(const float4*)&msgw[row * 64 + ((quad * 4) ^ qs)];
            const f32x4 sv = {vv.x, vv.y, vv.z, vv.w};
            __builtin_nontemporal_store(sv, (f32x4*)&Tb[(long)row * 1024 + c * 64 + quad * 4]);
        }
        asm volatile("s_waitcnt lgkmcnt(0)" ::: "memory");
    }
}

// ---------------- streaming gather-aggregate + residual + LN partials -------
// Block = 64-dst tile; wave w owns dsts [16w,16w+16); lane = (dl, fq).
// Each dl-group (4 lanes) sums its dst's T rows (2-edge unrolled for MLP).
__global__ __launch_bounds__(256, 4)
void k_agg2(const float* __restrict__ T, const float* __restrict__ hres,
            const int* __restrict__ elist, const int* __restrict__ seg,
            float* __restrict__ outb, float* __restrict__ pbuf)
{
    __shared__ float red[2][4][64];
    const int tid = threadIdx.x;
    const int w = tid >> 6, lane = tid & 63;
    const int dl = lane >> 2, fq = lane & 3;
    const int tile = blockIdx.x;
    const int gd = tile * 64 + w * 16 + dl;

    float4 a0 = {0,0,0,0}, a1 = a0, a2 = a0, a3 = a0;
    float4 b0 = a0, b1 = a0, b2 = a0, b3 = a0;

    if (gd < N_NODESC) {
        const int p0 = seg[gd * 16];
        const int p1 = seg[gd * 16 + 16];
        const float* __restrict__ Tf = T + 16 * fq;
        int p = p0;
        for (; p + 2 <= p1; p += 2) {
            const long t0 = (long)elist[p] * 64;
            const long t1 = (long)elist[p + 1] * 64;
            const float4 u0 = ntld(&Tf[t0 + 0]);
            const float4 u1 = ntld(&Tf[t0 + 4]);
            const float4 u2 = ntld(&Tf[t0 + 8]);
            const float4 u3 = ntld(&Tf[t0 + 12]);
            const float4 x0 = ntld(&Tf[t1 + 0]);
            const float4 x1 = ntld(&Tf[t1 + 4]);
            const float4 x2 = ntld(&Tf[t1 + 8]);
            const float4 x3 = ntld(&Tf[t1 + 12]);
            a0.x += u0.x; a0.y += u0.y; a0.z += u0.z; a0.w += u0.w;
            a1.x += u1.x; a1.y += u1.y; a1.z += u1.z; a1.w += u1.w;
            a2.x += u2.x; a2.y += u2.y; a2.z += u2.z; a2.w += u2.w;
            a3.x += u3.x; a3.y += u3.y; a3.z += u3.z; a3.w += u3.w;
            b0.x += x0.x; b0.y += x0.y; b0.z += x0.z; b0.w += x0.w;
            b1.x += x1.x; b1.y += x1.y; b1.z += x1.z; b1.w += x1.w;
            b2.x += x2.x; b2.y += x2.y; b2.z += x2.z; b2.w += x2.w;
            b3.x += x3.x; b3.y += x3.y; b3.z += x3.z; b3.w += x3.w;
        }
        if (p < p1) {
            const long t0 = (long)elist[p] * 64;
            const float4 u0 = ntld(&Tf[t0 + 0]);
            const float4 u1 = ntld(&Tf[t0 + 4]);
            const float4 u2 = ntld(&Tf[t0 + 8]);
            const float4 u3 = ntld(&Tf[t0 + 12]);
            a0.x += u0.x; a0.y += u0.y; a0.z += u0.z; a0.w += u0.w;
            a1.x += u1.x; a1.y += u1.y; a1.z += u1.z; a1.w += u1.w;
            a2.x += u2.x; a2.y += u2.y; a2.z += u2.z; a2.w += u2.w;
            a3.x += u3.x; a3.y += u3.y; a3.z += u3.z; a3.w += u3.w;
        }
        a0.x += b0.x; a0.y += b0.y; a0.z += b0.z; a0.w += b0.w;
        a1.x += b1.x; a1.y += b1.y; a1.z += b1.z; a1.w += b1.w;
        a2.x += b2.x; a2.y += b2.y; a2.z += b2.z; a2.w += b2.w;
        a3.x += b3.x; a3.y += b3.y; a3.z += b3.z; a3.w += b3.w;
    }

    // ---- epilogue (R8 verbatim): residual + store + LN partials ----
    float4 v[4] = {a0, a1, a2, a3};
    if (gd < N_NODESC) {
        const float4* __restrict__ hr = (const float4*)(hres + (long)gd * 64 + 16 * fq);
        float4* __restrict__ ob = (float4*)(outb + (long)gd * 64 + 16 * fq);
#pragma unroll
        for (int u = 0; u < 4; ++u) {
            const float4 r = hr[u];
            v[u].x += r.x; v[u].y += r.y; v[u].z += r.z; v[u].w += r.w;
            ob[u] = v[u];
        }
    } else {
#pragma unroll
        for (int u = 0; u < 4; ++u) v[u] = make_float4(0.f, 0.f, 0.f, 0.f);
    }
    float s1[16], s2[16];
#pragma unroll
    for (int u = 0; u < 4; ++u) {
        s1[4*u+0] = v[u].x; s2[4*u+0] = v[u].x * v[u].x;
        s1[4*u+1] = v[u].y; s2[4*u+1] = v[u].y * v[u].y;
        s1[4*u+2] = v[u].z; s2[4*u+2] = v[u].z * v[u].z;
        s1[4*u+3] = v[u].w; s2[4*u+3] = v[u].w * v[u].w;
    }
#pragma unroll
    for (int j = 0; j < 16; ++j) {
        s1[j] += __shfl_xor(s1[j], 4);  s2[j] += __shfl_xor(s2[j], 4);
        s1[j] += __shfl_xor(s1[j], 8);  s2[j] += __shfl_xor(s2[j], 8);
        s1[j] += __shfl_xor(s1[j], 16); s2[j] += __shfl_xor(s2[j], 16);
        s1[j] += __shfl_xor(s1[j], 32); s2[j] += __shfl_xor(s2[j], 32);
    }
    if (dl == 0) {
#pragma unroll
        for (int j = 0; j < 16; ++j) {
            red[0][w][16 * fq + j] = s1[j];
            red[1][w][16 * fq + j] = s2[j];
        }
    }
    __syncthreads();
    if (tid < 64) {
        const float t1 = red[0][0][tid] + red[0][1][tid] + red[0][2][tid] + red[0][3][tid];
        const float t2 = red[1][0][tid] + red[1][1][tid] + red[1][2][tid] + red[1][3][tid];
        pbuf[tile * 128 + tid] = t1;
        pbuf[tile * 128 + 64 + tid] = t2;
    }
}

// ---------------- reduce LN partials -> scale/shift ----------------
__global__ __launch_bounds__(1024)
void k_norm2(const float* __restrict__ pbuf, const float* __restrict__ g,
             const float* __restrict__ be, float* __restrict__ scale,
             float* __restrict__ shift)
{
    __shared__ float s[1024];
    const int t = threadIdx.x, j = t & 127, gg = t >> 7;
    float a = 0.f;
    for (int b = gg; b < NTILE; b += 8) a += pbuf[b * 128 + j];
    s[t] = a;
    __syncthreads();
    if (t < 128) {
        float tot = 0.f;
#pragma unroll
        for (int k = 0; k < 8; ++k) tot += s[j + 128 * k];
        s[t] = tot;
    }
    __syncthreads();
    if (t < 64) {
        const double mu  = (double)s[t] / (double)N_NODESC;
        const double var = (double)s[64 + t] / (double)N_NODESC - mu * mu;
        const double sc  = (double)g[t] / sqrt(var + (double)EPSF);
        scale[t] = (float)sc;
        shift[t] = (float)((double)be[t] - mu * sc);
    }
}

// ---------------- final projection (LN apply fused) ----------------
__global__ __launch_bounds__(256)
void k_out(const float* __restrict__ outb, const float* __restrict__ scale,
           const float* __restrict__ shift, const float* __restrict__ resW,
           const float* __restrict__ resb, float* __restrict__ out)
{
    const int n = blockIdx.x * 256 + threadIdx.x;
    if (n >= N_NODESC) return;
    float a0 = resb[0], a1 = resb[1];
    const float* __restrict__ r = outb + (long)n * 64;
#pragma unroll 8
    for (int e = 0; e < 64; ++e) {
        const float v = fmaxf(r[e] * scale[e] + shift[e], 0.f);
        a0 += v * resW[2 * e];
        a1 += v * resW[2 * e + 1];
    }
    out[2 * n] = a0;
    out[2 * n + 1] = a1;
}

extern "C" void kernel_launch(void* const* d_in, const int* in_sizes, int n_in,
                              void* d_out, int out_size, void* d_ws, size_t ws_size,
                              hipStream_t stream)
{
    const float* x      = (const float*)d_in[0];
    const float* M      = (const float*)d_in[1];
    const int*   src    = (const int*)d_in[2];
    const int*   dst    = (const int*)d_in[3];
    const int*   labels = (const int*)d_in[4];
    const int*   bidx   = (const int*)d_in[5];
    const float* resW   = (const float*)d_in[18];
    const float* resb   = (const float*)d_in[19];
    float* out = (float*)d_out;

    char* ws = (char*)d_ws;
    float*  scale = (float*)(ws + WS_SCALE);
    float*  shift = (float*)(ws + WS_SHIFT);
    int*    bsum  = (int*)(ws + WS_BSUM);
    float*  pbuf  = (float*)(ws + WS_PBUF);
    int*    hist  = (int*)(ws + WS_HIST);
    int*    fill  = (int*)(ws + WS_FILL);
    int*    seg   = (int*)(ws + WS_SEG);
    int*    elist = (int*)(ws + WS_ELIST);
    ushort* Ahi   = (ushort*)(ws + WS_AHI);
    ushort* Alo   = (ushort*)(ws + WS_ALO);
    ushort* hhi   = (ushort*)(ws + WS_HHI);
    ushort* hlo   = (ushort*)(ws + WS_HLO);
    float*  hB    = (float*)(ws + WS_HB);
    float*  outb  = (float*)(ws + WS_OUTB);
    float*  T     = (float*)(ws + WS_T);

    const int NB64 = (N_NODESC * 64 + 255) / 256;  // 12500

    // ---- preprocessing (graph + M constant across layers) ----
    hipMemsetAsync(hist, 0, 2 * (size_t)NKEYS * sizeof(int), stream);  // hist + fill
    k_hist<<<NEBLK, 256, 0, stream>>>(src, dst, labels, bidx, hist);
    k_bsum<<<NHBLK, 256, 0, stream>>>(hist, bsum);
    k_bscan2<<<1, 1024, 0, stream>>>(bsum);
    k_escan2<<<NHBLK, 256, 0, stream>>>(hist, bsum, seg);
    k_scat<<<NEBLK, 256, 0, stream>>>(src, dst, labels, bidx, seg, fill, elist);
    k_mfrag<<<16, 256, 0, stream>>>(M, Ahi, Alo);

    for (int l = 0; l < 3; ++l) {
        const float* W  = (const float*)d_in[6 + 4 * l];
        const float* b  = (const float*)d_in[7 + 4 * l];
        const float* g  = (const float*)d_in[8 + 4 * l];
        const float* be = (const float*)d_in[9 + 4 * l];

        if (l == 0) {
            k_h<<<NB64, 256, 0, stream>>>(x, W, b, hB, hhi, hlo, 128);
        } else {
            k_happly<<<N_NODESC / 4, 256, 0, stream>>>(outb, scale, shift, W, b,
                                                       hB, hhi, hlo);
        }
        k_T<<<NTBLK, 256, 0, stream>>>(hhi, hlo, Ahi, Alo, T);
        k_agg2<<<NTILE, 256, 0, stream>>>(T, hB, elist, seg, outb, pbuf);
        k_norm2<<<1, 1024, 0, stream>>>(pbuf, g, be, scale, shift);
    }
    k_out<<<(N_NODESC + 255) / 256, 256, 0, stream>>>(outb, scale, shift, resW, resb, out);
    (void)in_sizes; (void)n_in; (void)out_size; (void)ws_size;
}

// Round 15
// 650.758 us; speedup vs baseline: 1.6237x; 1.3887x over previous
//
#include <hip/hip_runtime.h>

// Problem constants
#define N_NODESC 50000
#define N_EDGESC 800000
#define EPSF 1e-5f
#define NTILE 782                   // ceil(50000/64)  (agg tiles)
#define NTBLK 1563                  // ceil(50000/32)  (k_T blocks)
#define NKEYS 800000                // 50000*16 (dst,combo) keys
#define NHBLK 3125                  // NKEYS/256
#define NEBLK 3125                  // 800000/256

typedef __attribute__((ext_vector_type(8))) short short8;
typedef __attribute__((ext_vector_type(16))) float f32x16;
typedef __attribute__((ext_vector_type(4))) float f32x4;

// ---- ws layout (bytes), total ~256.7 MB ----
#define WS_SCALE 0
#define WS_SHIFT 256
#define WS_BSUM  512                  // 3125 int
#define WS_PBUF  13056                // 782*128 f32 -> ends 413440
#define WS_HIST  413440               // 800000 int
#define WS_FILL  3613440              // 800000 int (contiguous after hist)
#define WS_SEG   6813440              // 800001 int
#define WS_ELIST 10013504             // 800000 int (tidx = src*16+c)
#define WS_AHI   13213504             // 128 KB
#define WS_ALO   13344576             // 128 KB
#define WS_HHI   13475648             // 50016*64 ushort (padded rows)
#define WS_HLO   19877696             // 50016*64 ushort
#define WS_HB    26279744             // 50000*64 f32
#define WS_OUTB  39079744             // 50000*64 f32
#define WS_T     51879744             // 50016*1024 f32 = 204.9 MB

// key = (dst, combo)
__device__ __forceinline__ int edge_key(int d, int c) {
    return d * 16 + c;
}

// ---------------- histogram ----------------
__global__ __launch_bounds__(256)
void k_hist(const int* __restrict__ src, const int* __restrict__ dst,
            const int* __restrict__ labels, const int* __restrict__ bidx,
            int* __restrict__ hist)
{
    const int e = blockIdx.x * 256 + threadIdx.x;
    if (e >= N_EDGESC) return;
    const int s = src[e], d = dst[e];
    const int c = (labels[d] * 2 + labels[s]) * 4 + bidx[e];
    atomicAdd(&hist[edge_key(d, c)], 1);
}

// ---------------- 3-level scan ----------------
__global__ __launch_bounds__(256)
void k_bsum(const int* __restrict__ hist, int* __restrict__ bsum)
{
    __shared__ int s[256];
    const int i = blockIdx.x * 256 + threadIdx.x;
    s[threadIdx.x] = hist[i];
    __syncthreads();
    for (int off = 128; off > 0; off >>= 1) {
        if (threadIdx.x < off) s[threadIdx.x] += s[threadIdx.x + off];
        __syncthreads();
    }
    if (threadIdx.x == 0) bsum[blockIdx.x] = s[0];
}

__global__ __launch_bounds__(1024)
void k_bscan2(int* __restrict__ bsum)   // in-place exclusive scan of NHBLK entries
{
    __shared__ int s[1024];
    const int t = threadIdx.x;
    int v[4]; int tot = 0;
#pragma unroll
    for (int j = 0; j < 4; ++j) {
        const int i = t * 4 + j;
        v[j] = (i < NHBLK) ? bsum[i] : 0;
        tot += v[j];
    }
    s[t] = tot; __syncthreads();
    for (int off = 1; off < 1024; off <<= 1) {
        const int x = (t >= off) ? s[t - off] : 0;
        __syncthreads();
        s[t] += x;
        __syncthreads();
    }
    int base = s[t] - tot;
#pragma unroll
    for (int j = 0; j < 4; ++j) {
        const int i = t * 4 + j;
        if (i < NHBLK) bsum[i] = base;
        base += v[j];
    }
}

__global__ __launch_bounds__(256)
void k_escan2(const int* __restrict__ hist, const int* __restrict__ bsum,
              int* __restrict__ seg)
{
    __shared__ int s[256];
    const int t = threadIdx.x;
    const int i = blockIdx.x * 256 + t;
    const int v = hist[i];
    s[t] = v; __syncthreads();
    for (int off = 1; off < 256; off <<= 1) {
        const int x = (t >= off) ? s[t - off] : 0;
        __syncthreads();
        s[t] += x;
        __syncthreads();
    }
    const int incl = s[t];
    seg[i] = bsum[blockIdx.x] + incl - v;
    if (i == NKEYS - 1) seg[NKEYS] = bsum[blockIdx.x] + incl;
}

__global__ __launch_bounds__(256)
void k_scat(const int* __restrict__ src, const int* __restrict__ dst,
            const int* __restrict__ labels, const int* __restrict__ bidx,
            const int* __restrict__ seg, int* __restrict__ fill,
            int* __restrict__ elist)
{
    const int e = blockIdx.x * 256 + threadIdx.x;
    if (e >= N_EDGESC) return;
    const int s = src[e], d = dst[e];
    const int c = (labels[d] * 2 + labels[s]) * 4 + bidx[e];
    const int k = edge_key(d, c);
    const int pos = seg[k] + atomicAdd(&fill[k], 1);
    elist[pos] = s * 16 + c;               // tidx into T
}

// ---- MFMA A-fragments (split bf16 hi/lo), layout verified R5/R8 ----
__global__ void k_mfrag(const float* __restrict__ M, ushort* __restrict__ Ahi,
                        ushort* __restrict__ Alo)
{
    const int c = blockIdx.x;
    for (int slot = threadIdx.x; slot < 512; slot += 256) {
        const int t = slot >> 8, s = (slot >> 6) & 3, lane = slot & 63;
        const int row = (lane & 31) + 32 * t;
        const int kb = 16 * s + 8 * (lane >> 5);
        const int fid = ((c * 2 + t) * 4 + s) * 64 + lane;
#pragma unroll
        for (int j = 0; j < 8; ++j) {
            const float v = M[c * 4096 + row * 64 + kb + j];
            const unsigned b = __float_as_uint(v);
            const float lof = v - __uint_as_float(b & 0xFFFF0000u);
            Ahi[fid * 8 + j] = (ushort)(b >> 16);
            Alo[fid * 8 + j] = (ushort)(__float_as_uint(lof) >> 16);
        }
    }
}

// ---------------- h = in @ W + b, + split-bf16 outputs ----------------
__global__ __launch_bounds__(256)
void k_h(const float* __restrict__ in, const float* __restrict__ W,
         const float* __restrict__ b, float* __restrict__ h,
         ushort* __restrict__ hhi, ushort* __restrict__ hlo, const int F)
{
    const int t = blockIdx.x * 256 + threadIdx.x;
    if (t >= N_NODESC * 64) return;
    const int n = t >> 6, e = t & 63;
    const float* __restrict__ xr = in + (long)n * F;
    float acc = b[e];
    for (int f = 0; f < F; f += 4) {
        acc += xr[f]     * W[f * 64 + e];
        acc += xr[f + 1] * W[(f + 1) * 64 + e];
        acc += xr[f + 2] * W[(f + 2) * 64 + e];
        acc += xr[f + 3] * W[(f + 3) * 64 + e];
    }
    h[t] = acc;
    const unsigned bb = __float_as_uint(acc);
    const float lof = acc - __uint_as_float(bb & 0xFFFF0000u);
    hhi[t] = (ushort)(bb >> 16);
    hlo[t] = (ushort)(__float_as_uint(lof) >> 16);
}

// ---------------- fused LN-apply + relu + next-layer GEMM + split -----------
__global__ __launch_bounds__(256)
void k_happly(const float* __restrict__ outb, const float* __restrict__ scale,
              const float* __restrict__ shift, const float* __restrict__ W,
              const float* __restrict__ b, float* __restrict__ h,
              ushort* __restrict__ hhi, ushort* __restrict__ hlo)
{
    __shared__ float act[4][64];
    const int nl = threadIdx.x >> 6, o = threadIdx.x & 63;
    const int n = blockIdx.x * 4 + nl;
    const float v = outb[(long)n * 64 + o] * scale[o] + shift[o];
    act[nl][o] = fmaxf(v, 0.f);
    __syncthreads();
    float a = b[o];
#pragma unroll 16
    for (int f = 0; f < 64; ++f) a += act[nl][f] * W[f * 64 + o];
    const long t = (long)n * 64 + o;
    h[t] = a;
    const unsigned bb = __float_as_uint(a);
    const float lof = a - __uint_as_float(bb & 0xFFFF0000u);
    hhi[t] = (ushort)(bb >> 16);
    hlo[t] = (ushort)(__float_as_uint(lof) >> 16);
}

// ---------------- dense transform table: T[n][c*64+o] = (M_c h_n)[o] --------
// Block = 32 nodes; wave w handles combos w, w+4, w+8, w+12. B-frags from
// SEQUENTIAL hhi/hlo rows. C staged via R8 LDS swizzle, stored COALESCED
// with PLAIN stores (T stays L3-resident for the gather pass).
__global__ __launch_bounds__(256, 3)
void k_T(const ushort* __restrict__ hhi, const ushort* __restrict__ hlo,
         const ushort* __restrict__ Ahi, const ushort* __restrict__ Alo,
         float* __restrict__ T)
{
    __shared__ float msg[4][2048];        // per-wave 32 nodes x 64 feats (32 KB)
    const int tid = threadIdx.x;
    const int w = tid >> 6, lane = tid & 63;
    const int col = lane & 31, hig = lane >> 5;
    const int node = blockIdx.x * 32 + col;

    const ushort* __restrict__ rh = hhi + (long)node * 64 + hig * 8;
    const ushort* __restrict__ rl = hlo + (long)node * 64 + hig * 8;
    short8 bh[4], bl[4];
#pragma unroll
    for (int s = 0; s < 4; ++s) {
        bh[s] = *(const short8*)&rh[s * 16];
        bl[s] = *(const short8*)&rl[s * 16];
    }
    float* __restrict__ msgw = msg[w];
    float* __restrict__ Tb = T + (long)blockIdx.x * 32768;    // 32 rows x 1024

    for (int ci = 0; ci < 4; ++ci) {
        const int c = w + 4 * ci;
        f32x16 c0, c1;
#pragma unroll
        for (int i = 0; i < 16; ++i) { c0[i] = 0.f; c1[i] = 0.f; }
#pragma unroll
        for (int s = 0; s < 4; ++s) {
            const int fidb = (c * 8 + s) * 64 + lane;
            const short8 a0h = *(const short8*)&Ahi[fidb * 8];
            const short8 a1h = *(const short8*)&Ahi[(fidb + 256) * 8];
            const short8 a0l = *(const short8*)&Alo[fidb * 8];
            const short8 a1l = *(const short8*)&Alo[(fidb + 256) * 8];
            c0 = __builtin_amdgcn_mfma_f32_32x32x16_bf16(a0h, bh[s], c0, 0, 0, 0);
            c1 = __builtin_amdgcn_mfma_f32_32x32x16_bf16(a1h, bh[s], c1, 0, 0, 0);
            c0 = __builtin_amdgcn_mfma_f32_32x32x16_bf16(a0h, bl[s], c0, 0, 0, 0);
            c1 = __builtin_amdgcn_mfma_f32_32x32x16_bf16(a1h, bl[s], c1, 0, 0, 0);
            c0 = __builtin_amdgcn_mfma_f32_32x32x16_bf16(a0l, bh[s], c0, 0, 0, 0);
            c1 = __builtin_amdgcn_mfma_f32_32x32x16_bf16(a1l, bh[s], c1, 0, 0, 0);
        }

        // stage C tile to LDS: msg[col][feat], feat XOR-swizzled (R8 pattern)
        const int sw = (col & 7) << 3;
        const int cb = col * 64;
#pragma unroll
        for (int rq = 0; rq < 4; ++rq) {
            const int fb = 8 * rq + 4 * hig;       // C row = (r&3)+8(r>>2)+4hig
            float4 v0 = {c0[4*rq], c0[4*rq+1], c0[4*rq+2], c0[4*rq+3]};
            float4 v1 = {c1[4*rq], c1[4*rq+1], c1[4*rq+2], c1[4*rq+3]};
            *(float4*)&msgw[cb + (fb ^ sw)] = v0;
            *(float4*)&msgw[cb + ((fb + 32) ^ sw)] = v1;
        }
        asm volatile("s_waitcnt lgkmcnt(0)" ::: "memory");

        // coalesced store-out: lanes 0-15 -> one node-row's 256B chunk
#pragma unroll
        for (int i = 0; i < 8; ++i) {
            const int idx = i * 64 + lane;
            const int row = idx >> 4, quad = idx & 15;
            const int qs = (row & 7) << 3;
            const float4 vv = *(const float4*)&msgw[row * 64 + ((quad * 4) ^ qs)];
            *(float4*)&Tb[(long)row * 1024 + c * 64 + quad * 4] = vv;
        }
        asm volatile("s_waitcnt lgkmcnt(0)" ::: "memory");
    }
}

// ---------------- streaming gather-aggregate + residual + LN partials -------
// Block = 64-dst tile; wave w owns dsts [16w,16w+16); lane = (dl, fq).
// 4-edge unrolled gather (16 independent 16B loads in flight per lane).
__global__ __launch_bounds__(256, 4)
void k_agg2(const float* __restrict__ T, const float* __restrict__ hres,
            const int* __restrict__ elist, const int* __restrict__ seg,
            float* __restrict__ outb, float* __restrict__ pbuf)
{
    __shared__ float red[2][4][64];
    const int tid = threadIdx.x;
    const int w = tid >> 6, lane = tid & 63;
    const int dl = lane >> 2, fq = lane & 3;
    const int tile = blockIdx.x;
    const int gd = tile * 64 + w * 16 + dl;

    float4 a0 = {0,0,0,0}, a1 = a0, a2 = a0, a3 = a0;

    if (gd < N_NODESC) {
        const int p0 = seg[gd * 16];
        const int p1 = seg[gd * 16 + 16];
        const float* __restrict__ Tf = T + 16 * fq;
        int p = p0;
        for (; p + 4 <= p1; p += 4) {
            const long t0 = (long)elist[p] * 64;
            const long t1 = (long)elist[p + 1] * 64;
            const long t2 = (long)elist[p + 2] * 64;
            const long t3 = (long)elist[p + 3] * 64;
            const float4 u00 = *(const float4*)&Tf[t0 + 0];
            const float4 u01 = *(const float4*)&Tf[t0 + 4];
            const float4 u02 = *(const float4*)&Tf[t0 + 8];
            const float4 u03 = *(const float4*)&Tf[t0 + 12];
            const float4 u10 = *(const float4*)&Tf[t1 + 0];
            const float4 u11 = *(const float4*)&Tf[t1 + 4];
            const float4 u12 = *(const float4*)&Tf[t1 + 8];
            const float4 u13 = *(const float4*)&Tf[t1 + 12];
            const float4 u20 = *(const float4*)&Tf[t2 + 0];
            const float4 u21 = *(const float4*)&Tf[t2 + 4];
            const float4 u22 = *(const float4*)&Tf[t2 + 8];
            const float4 u23 = *(const float4*)&Tf[t2 + 12];
            const float4 u30 = *(const float4*)&Tf[t3 + 0];
            const float4 u31 = *(const float4*)&Tf[t3 + 4];
            const float4 u32 = *(const float4*)&Tf[t3 + 8];
            const float4 u33 = *(const float4*)&Tf[t3 + 12];
            a0.x += u00.x + u10.x + u20.x + u30.x;
            a0.y += u00.y + u10.y + u20.y + u30.y;
            a0.z += u00.z + u10.z + u20.z + u30.z;
            a0.w += u00.w + u10.w + u20.w + u30.w;
            a1.x += u01.x + u11.x + u21.x + u31.x;
            a1.y += u01.y + u11.y + u21.y + u31.y;
            a1.z += u01.z + u11.z + u21.z + u31.z;
            a1.w += u01.w + u11.w + u21.w + u31.w;
            a2.x += u02.x + u12.x + u22.x + u32.x;
            a2.y += u02.y + u12.y + u22.y + u32.y;
            a2.z += u02.z + u12.z + u22.z + u32.z;
            a2.w += u02.w + u12.w + u22.w + u32.w;
            a3.x += u03.x + u13.x + u23.x + u33.x;
            a3.y += u03.y + u13.y + u23.y + u33.y;
            a3.z += u03.z + u13.z + u23.z + u33.z;
            a3.w += u03.w + u13.w + u23.w + u33.w;
        }
        for (; p < p1; ++p) {
            const long t0 = (long)elist[p] * 64;
            const float4 u0 = *(const float4*)&Tf[t0 + 0];
            const float4 u1 = *(const float4*)&Tf[t0 + 4];
            const float4 u2 = *(const float4*)&Tf[t0 + 8];
            const float4 u3 = *(const float4*)&Tf[t0 + 12];
            a0.x += u0.x; a0.y += u0.y; a0.z += u0.z; a0.w += u0.w;
            a1.x += u1.x; a1.y += u1.y; a1.z += u1.z; a1.w += u1.w;
            a2.x += u2.x; a2.y += u2.y; a2.z += u2.z; a2.w += u2.w;
            a3.x += u3.x; a3.y += u3.y; a3.z += u3.z; a3.w += u3.w;
        }
    }

    // ---- epilogue (R8 verbatim): residual + store + LN partials ----
    float4 v[4] = {a0, a1, a2, a3};
    if (gd < N_NODESC) {
        const float4* __restrict__ hr = (const float4*)(hres + (long)gd * 64 + 16 * fq);
        float4* __restrict__ ob = (float4*)(outb + (long)gd * 64 + 16 * fq);
#pragma unroll
        for (int u = 0; u < 4; ++u) {
            const float4 r = hr[u];
            v[u].x += r.x; v[u].y += r.y; v[u].z += r.z; v[u].w += r.w;
            ob[u] = v[u];
        }
    } else {
#pragma unroll
        for (int u = 0; u < 4; ++u) v[u] = make_float4(0.f, 0.f, 0.f, 0.f);
    }
    float s1[16], s2[16];
#pragma unroll
    for (int u = 0; u < 4; ++u) {
        s1[4*u+0] = v[u].x; s2[4*u+0] = v[u].x * v[u].x;
        s1[4*u+1] = v[u].y; s2[4*u+1] = v[u].y * v[u].y;
        s1[4*u+2] = v[u].z; s2[4*u+2] = v[u].z * v[u].z;
        s1[4*u+3] = v[u].w; s2[4*u+3] = v[u].w * v[u].w;
    }
#pragma unroll
    for (int j = 0; j < 16; ++j) {
        s1[j] += __shfl_xor(s1[j], 4);  s2[j] += __shfl_xor(s2[j], 4);
        s1[j] += __shfl_xor(s1[j], 8);  s2[j] += __shfl_xor(s2[j], 8);
        s1[j] += __shfl_xor(s1[j], 16); s2[j] += __shfl_xor(s2[j], 16);
        s1[j] += __shfl_xor(s1[j], 32); s2[j] += __shfl_xor(s2[j], 32);
    }
    if (dl == 0) {
#pragma unroll
        for (int j = 0; j < 16; ++j) {
            red[0][w][16 * fq + j] = s1[j];
            red[1][w][16 * fq + j] = s2[j];
        }
    }
    __syncthreads();
    if (tid < 64) {
        const float t1 = red[0][0][tid] + red[0][1][tid] + red[0][2][tid] + red[0][3][tid];
        const float t2 = red[1][0][tid] + red[1][1][tid] + red[1][2][tid] + red[1][3][tid];
        pbuf[tile * 128 + tid] = t1;
        pbuf[tile * 128 + 64 + tid] = t2;
    }
}

// ---------------- reduce LN partials -> scale/shift ----------------
__global__ __launch_bounds__(1024)
void k_norm2(const float* __restrict__ pbuf, const float* __restrict__ g,
             const float* __restrict__ be, float* __restrict__ scale,
             float* __restrict__ shift)
{
    __shared__ float s[1024];
    const int t = threadIdx.x, j = t & 127, gg = t >> 7;
    float a = 0.f;
    for (int b = gg; b < NTILE; b += 8) a += pbuf[b * 128 + j];
    s[t] = a;
    __syncthreads();
    if (t < 128) {
        float tot = 0.f;
#pragma unroll
        for (int k = 0; k < 8; ++k) tot += s[j + 128 * k];
        s[t] = tot;
    }
    __syncthreads();
    if (t < 64) {
        const double mu  = (double)s[t] / (double)N_NODESC;
        const double var = (double)s[64 + t] / (double)N_NODESC - mu * mu;
        const double sc  = (double)g[t] / sqrt(var + (double)EPSF);
        scale[t] = (float)sc;
        shift[t] = (float)((double)be[t] - mu * sc);
    }
}

// ---------------- final projection (LN apply fused) ----------------
__global__ __launch_bounds__(256)
void k_out(const float* __restrict__ outb, const float* __restrict__ scale,
           const float* __restrict__ shift, const float* __restrict__ resW,
           const float* __restrict__ resb, float* __restrict__ out)
{
    const int n = blockIdx.x * 256 + threadIdx.x;
    if (n >= N_NODESC) return;
    float a0 = resb[0], a1 = resb[1];
    const float* __restrict__ r = outb + (long)n * 64;
#pragma unroll 8
    for (int e = 0; e < 64; ++e) {
        const float v = fmaxf(r[e] * scale[e] + shift[e], 0.f);
        a0 += v * resW[2 * e];
        a1 += v * resW[2 * e + 1];
    }
    out[2 * n] = a0;
    out[2 * n + 1] = a1;
}

extern "C" void kernel_launch(void* const* d_in, const int* in_sizes, int n_in,
                              void* d_out, int out_size, void* d_ws, size_t ws_size,
                              hipStream_t stream)
{
    const float* x      = (const float*)d_in[0];
    const float* M      = (const float*)d_in[1];
    const int*   src    = (const int*)d_in[2];
    const int*   dst    = (const int*)d_in[3];
    const int*   labels = (const int*)d_in[4];
    const int*   bidx   = (const int*)d_in[5];
    const float* resW   = (const float*)d_in[18];
    const float* resb   = (const float*)d_in[19];
    float* out = (float*)d_out;

    char* ws = (char*)d_ws;
    float*  scale = (float*)(ws + WS_SCALE);
    float*  shift = (float*)(ws + WS_SHIFT);
    int*    bsum  = (int*)(ws + WS_BSUM);
    float*  pbuf  = (float*)(ws + WS_PBUF);
    int*    hist  = (int*)(ws + WS_HIST);
    int*    fill  = (int*)(ws + WS_FILL);
    int*    seg   = (int*)(ws + WS_SEG);
    int*    elist = (int*)(ws + WS_ELIST);
    ushort* Ahi   = (ushort*)(ws + WS_AHI);
    ushort* Alo   = (ushort*)(ws + WS_ALO);
    ushort* hhi   = (ushort*)(ws + WS_HHI);
    ushort* hlo   = (ushort*)(ws + WS_HLO);
    float*  hB    = (float*)(ws + WS_HB);
    float*  outb  = (float*)(ws + WS_OUTB);
    float*  T     = (float*)(ws + WS_T);

    const int NB64 = (N_NODESC * 64 + 255) / 256;  // 12500

    // ---- preprocessing (graph + M constant across layers) ----
    hipMemsetAsync(hist, 0, 2 * (size_t)NKEYS * sizeof(int), stream);  // hist + fill
    k_hist<<<NEBLK, 256, 0, stream>>>(src, dst, labels, bidx, hist);
    k_bsum<<<NHBLK, 256, 0, stream>>>(hist, bsum);
    k_bscan2<<<1, 1024, 0, stream>>>(bsum);
    k_escan2<<<NHBLK, 256, 0, stream>>>(hist, bsum, seg);
    k_scat<<<NEBLK, 256, 0, stream>>>(src, dst, labels, bidx, seg, fill, elist);
    k_mfrag<<<16, 256, 0, stream>>>(M, Ahi, Alo);

    for (int l = 0; l < 3; ++l) {
        const float* W  = (const float*)d_in[6 + 4 * l];
        const float* b  = (const float*)d_in[7 + 4 * l];
        const float* g  = (const float*)d_in[8 + 4 * l];
        const float* be = (const float*)d_in[9 + 4 * l];

        if (l == 0) {
            k_h<<<NB64, 256, 0, stream>>>(x, W, b, hB, hhi, hlo, 128);
        } else {
            k_happly<<<N_NODESC / 4, 256, 0, stream>>>(outb, scale, shift, W, b,
                                                       hB, hhi, hlo);
        }
        k_T<<<NTBLK, 256, 0, stream>>>(hhi, hlo, Ahi, Alo, T);
        k_agg2<<<NTILE, 256, 0, stream>>>(T, hB, elist, seg, outb, pbuf);
        k_norm2<<<1, 1024, 0, stream>>>(pbuf, g, be, scale, shift);
    }
    k_out<<<(N_NODESC + 255) / 256, 256, 0, stream>>>(outb, scale, shift, resW, resb, out);
    (void)in_sizes; (void)n_in; (void)out_size; (void)ws_size;
}

// Round 16
// 615.740 us; speedup vs baseline: 1.7160x; 1.0569x over previous
//
#include <hip/hip_runtime.h>

// Problem constants
#define N_NODESC 50000
#define N_EDGESC 800000
#define EPSF 1e-5f
#define NTILE 782                   // ceil(50000/64)  (agg tiles)
#define NTBLK 1563                  // ceil(50000/32)  (k_T blocks)
#define NKEYS 800000                // 50000*16 (dst,combo) keys
#define NHBLK 3125                  // NKEYS/256
#define NEBLK 3125                  // 800000/256

typedef __attribute__((ext_vector_type(8))) short short8;
typedef __attribute__((ext_vector_type(16))) float f32x16;
typedef __attribute__((ext_vector_type(4))) float f32x4;

// ---- ws layout (bytes), total ~256.7 MB ----
#define WS_SCALE 0
#define WS_SHIFT 256
#define WS_BSUM  512                  // 3125 int
#define WS_PBUF  13056                // 782*128 f32 -> ends 413440
#define WS_HIST  413440               // 800000 int
#define WS_FILL  3613440              // 800000 int (contiguous after hist)
#define WS_SEG   6813440              // 800001 int
#define WS_ELIST 10013504             // 800000 int (tidx = src*16+c)
#define WS_AHI   13213504             // 128 KB
#define WS_ALO   13344576             // 128 KB
#define WS_HHI   13475648             // 50016*64 ushort (padded rows)
#define WS_HLO   19877696             // 50016*64 ushort
#define WS_HB    26279744             // 50000*64 f32
#define WS_OUTB  39079744             // 50000*64 f32
#define WS_T     51879744             // 50016*1024 f32 = 204.9 MB

// key = (dst, combo)
__device__ __forceinline__ int edge_key(int d, int c) {
    return d * 16 + c;
}

__device__ __forceinline__ ushort bf_hi(float v) {
    return (ushort)(__float_as_uint(v) >> 16);
}
__device__ __forceinline__ ushort bf_lo(float v) {
    const unsigned b = __float_as_uint(v);
    const float lof = v - __uint_as_float(b & 0xFFFF0000u);
    return (ushort)(__float_as_uint(lof) >> 16);
}

// ---------------- histogram ----------------
__global__ __launch_bounds__(256)
void k_hist(const int* __restrict__ src, const int* __restrict__ dst,
            const int* __restrict__ labels, const int* __restrict__ bidx,
            int* __restrict__ hist)
{
    const int e = blockIdx.x * 256 + threadIdx.x;
    if (e >= N_EDGESC) return;
    const int s = src[e], d = dst[e];
    const int c = (labels[d] * 2 + labels[s]) * 4 + bidx[e];
    atomicAdd(&hist[edge_key(d, c)], 1);
}

// ---------------- 3-level scan ----------------
__global__ __launch_bounds__(256)
void k_bsum(const int* __restrict__ hist, int* __restrict__ bsum)
{
    __shared__ int s[256];
    const int i = blockIdx.x * 256 + threadIdx.x;
    s[threadIdx.x] = hist[i];
    __syncthreads();
    for (int off = 128; off > 0; off >>= 1) {
        if (threadIdx.x < off) s[threadIdx.x] += s[threadIdx.x + off];
        __syncthreads();
    }
    if (threadIdx.x == 0) bsum[blockIdx.x] = s[0];
}

__global__ __launch_bounds__(1024)
void k_bscan2(int* __restrict__ bsum)   // in-place exclusive scan of NHBLK entries
{
    __shared__ int s[1024];
    const int t = threadIdx.x;
    int v[4]; int tot = 0;
#pragma unroll
    for (int j = 0; j < 4; ++j) {
        const int i = t * 4 + j;
        v[j] = (i < NHBLK) ? bsum[i] : 0;
        tot += v[j];
    }
    s[t] = tot; __syncthreads();
    for (int off = 1; off < 1024; off <<= 1) {
        const int x = (t >= off) ? s[t - off] : 0;
        __syncthreads();
        s[t] += x;
        __syncthreads();
    }
    int base = s[t] - tot;
#pragma unroll
    for (int j = 0; j < 4; ++j) {
        const int i = t * 4 + j;
        if (i < NHBLK) bsum[i] = base;
        base += v[j];
    }
}

__global__ __launch_bounds__(256)
void k_escan2(const int* __restrict__ hist, const int* __restrict__ bsum,
              int* __restrict__ seg)
{
    __shared__ int s[256];
    const int t = threadIdx.x;
    const int i = blockIdx.x * 256 + t;
    const int v = hist[i];
    s[t] = v; __syncthreads();
    for (int off = 1; off < 256; off <<= 1) {
        const int x = (t >= off) ? s[t - off] : 0;
        __syncthreads();
        s[t] += x;
        __syncthreads();
    }
    const int incl = s[t];
    seg[i] = bsum[blockIdx.x] + incl - v;
    if (i == NKEYS - 1) seg[NKEYS] = bsum[blockIdx.x] + incl;
}

__global__ __launch_bounds__(256)
void k_scat(const int* __restrict__ src, const int* __restrict__ dst,
            const int* __restrict__ labels, const int* __restrict__ bidx,
            const int* __restrict__ seg, int* __restrict__ fill,
            int* __restrict__ elist)
{
    const int e = blockIdx.x * 256 + threadIdx.x;
    if (e >= N_EDGESC) return;
    const int s = src[e], d = dst[e];
    const int c = (labels[d] * 2 + labels[s]) * 4 + bidx[e];
    const int k = edge_key(d, c);
    const int pos = seg[k] + atomicAdd(&fill[k], 1);
    elist[pos] = s * 16 + c;               // tidx into T
}

// ---- MFMA A-fragments (split bf16 hi/lo), layout verified R5/R8 ----
__global__ void k_mfrag(const float* __restrict__ M, ushort* __restrict__ Ahi,
                        ushort* __restrict__ Alo)
{
    const int c = blockIdx.x;
    for (int slot = threadIdx.x; slot < 512; slot += 256) {
        const int t = slot >> 8, s = (slot >> 6) & 3, lane = slot & 63;
        const int row = (lane & 31) + 32 * t;
        const int kb = 16 * s + 8 * (lane >> 5);
        const int fid = ((c * 2 + t) * 4 + s) * 64 + lane;
#pragma unroll
        for (int j = 0; j < 8; ++j) {
            const float v = M[c * 4096 + row * 64 + kb + j];
            Ahi[fid * 8 + j] = bf_hi(v);
            Alo[fid * 8 + j] = bf_lo(v);
        }
    }
}

// ---------------- h = in @ W + b, + split-bf16 (4 outputs/thread) -----------
__global__ __launch_bounds__(256)
void k_h(const float* __restrict__ in, const float* __restrict__ W,
         const float* __restrict__ b, float* __restrict__ h,
         ushort* __restrict__ hhi, ushort* __restrict__ hlo, const int F)
{
    const int t = blockIdx.x * 256 + threadIdx.x;
    const int n = t >> 4, q = t & 15;
    if (n >= N_NODESC) return;
    const int e0 = q * 4;
    const float* __restrict__ xr = in + (long)n * F;
    float a0 = b[e0], a1 = b[e0 + 1], a2 = b[e0 + 2], a3 = b[e0 + 3];
    for (int f = 0; f < F; f += 4) {
        const float4 xv = *(const float4*)&xr[f];
        const float4 w0 = *(const float4*)&W[(f + 0) * 64 + e0];
        const float4 w1 = *(const float4*)&W[(f + 1) * 64 + e0];
        const float4 w2 = *(const float4*)&W[(f + 2) * 64 + e0];
        const float4 w3 = *(const float4*)&W[(f + 3) * 64 + e0];
        a0 += xv.x * w0.x + xv.y * w1.x + xv.z * w2.x + xv.w * w3.x;
        a1 += xv.x * w0.y + xv.y * w1.y + xv.z * w2.y + xv.w * w3.y;
        a2 += xv.x * w0.z + xv.y * w1.z + xv.z * w2.z + xv.w * w3.z;
        a3 += xv.x * w0.w + xv.y * w1.w + xv.z * w2.w + xv.w * w3.w;
    }
    const long o = (long)n * 64 + e0;
    const float4 hv = {a0, a1, a2, a3};
    *(float4*)&h[o] = hv;
    ushort4 hi4, lo4;
    hi4.x = bf_hi(a0); hi4.y = bf_hi(a1); hi4.z = bf_hi(a2); hi4.w = bf_hi(a3);
    lo4.x = bf_lo(a0); lo4.y = bf_lo(a1); lo4.z = bf_lo(a2); lo4.w = bf_lo(a3);
    *(ushort4*)&hhi[o] = hi4;
    *(ushort4*)&hlo[o] = lo4;
}

// ---------------- fused LN-apply + relu + next-layer GEMM + split -----------
// Block = 16 nodes x 16 quad-threads. act staged in padded LDS.
__global__ __launch_bounds__(256)
void k_happly(const float* __restrict__ outb, const float* __restrict__ scale,
              const float* __restrict__ shift, const float* __restrict__ W,
              const float* __restrict__ b, float* __restrict__ h,
              ushort* __restrict__ hhi, ushort* __restrict__ hlo)
{
    __shared__ float act[16][68];
    const int nl = threadIdx.x >> 4, q = threadIdx.x & 15;
    const int n = blockIdx.x * 16 + nl;
    const int e0 = q * 4;
    {
        const float4 ov = *(const float4*)&outb[(long)n * 64 + e0];
        act[nl][e0 + 0] = fmaxf(ov.x * scale[e0 + 0] + shift[e0 + 0], 0.f);
        act[nl][e0 + 1] = fmaxf(ov.y * scale[e0 + 1] + shift[e0 + 1], 0.f);
        act[nl][e0 + 2] = fmaxf(ov.z * scale[e0 + 2] + shift[e0 + 2], 0.f);
        act[nl][e0 + 3] = fmaxf(ov.w * scale[e0 + 3] + shift[e0 + 3], 0.f);
    }
    __syncthreads();
    float a0 = b[e0], a1 = b[e0 + 1], a2 = b[e0 + 2], a3 = b[e0 + 3];
    const float* __restrict__ ar = act[nl];
#pragma unroll 4
    for (int f = 0; f < 64; f += 4) {
        const float x0 = ar[f], x1 = ar[f + 1], x2 = ar[f + 2], x3 = ar[f + 3];
        const float4 w0 = *(const float4*)&W[(f + 0) * 64 + e0];
        const float4 w1 = *(const float4*)&W[(f + 1) * 64 + e0];
        const float4 w2 = *(const float4*)&W[(f + 2) * 64 + e0];
        const float4 w3 = *(const float4*)&W[(f + 3) * 64 + e0];
        a0 += x0 * w0.x + x1 * w1.x + x2 * w2.x + x3 * w3.x;
        a1 += x0 * w0.y + x1 * w1.y + x2 * w2.y + x3 * w3.y;
        a2 += x0 * w0.z + x1 * w1.z + x2 * w2.z + x3 * w3.z;
        a3 += x0 * w0.w + x1 * w1.w + x2 * w2.w + x3 * w3.w;
    }
    const long o = (long)n * 64 + e0;
    const float4 hv = {a0, a1, a2, a3};
    *(float4*)&h[o] = hv;
    ushort4 hi4, lo4;
    hi4.x = bf_hi(a0); hi4.y = bf_hi(a1); hi4.z = bf_hi(a2); hi4.w = bf_hi(a3);
    lo4.x = bf_lo(a0); lo4.y = bf_lo(a1); lo4.z = bf_lo(a2); lo4.w = bf_lo(a3);
    *(ushort4*)&hhi[o] = hi4;
    *(ushort4*)&hlo[o] = lo4;
}

// ---------------- dense transform table: T[n][c*64+o] = (M_c h_n)[o] --------
// Block = 32 nodes; wave w handles combos w, w+4, w+8, w+12. B-frags from
// SEQUENTIAL hhi/hlo rows. C staged via R8 LDS swizzle, stored COALESCED
// with PLAIN stores (T stays L3-resident for the gather pass).
__global__ __launch_bounds__(256, 3)
void k_T(const ushort* __restrict__ hhi, const ushort* __restrict__ hlo,
         const ushort* __restrict__ Ahi, const ushort* __restrict__ Alo,
         float* __restrict__ T)
{
    __shared__ float msg[4][2048];        // per-wave 32 nodes x 64 feats (32 KB)
    const int tid = threadIdx.x;
    const int w = tid >> 6, lane = tid & 63;
    const int col = lane & 31, hig = lane >> 5;
    const int node = blockIdx.x * 32 + col;

    const ushort* __restrict__ rh = hhi + (long)node * 64 + hig * 8;
    const ushort* __restrict__ rl = hlo + (long)node * 64 + hig * 8;
    short8 bh[4], bl[4];
#pragma unroll
    for (int s = 0; s < 4; ++s) {
        bh[s] = *(const short8*)&rh[s * 16];
        bl[s] = *(const short8*)&rl[s * 16];
    }
    float* __restrict__ msgw = msg[w];
    float* __restrict__ Tb = T + (long)blockIdx.x * 32768;    // 32 rows x 1024

    for (int ci = 0; ci < 4; ++ci) {
        const int c = w + 4 * ci;
        f32x16 c0, c1;
#pragma unroll
        for (int i = 0; i < 16; ++i) { c0[i] = 0.f; c1[i] = 0.f; }
#pragma unroll
        for (int s = 0; s < 4; ++s) {
            const int fidb = (c * 8 + s) * 64 + lane;
            const short8 a0h = *(const short8*)&Ahi[fidb * 8];
            const short8 a1h = *(const short8*)&Ahi[(fidb + 256) * 8];
            const short8 a0l = *(const short8*)&Alo[fidb * 8];
            const short8 a1l = *(const short8*)&Alo[(fidb + 256) * 8];
            c0 = __builtin_amdgcn_mfma_f32_32x32x16_bf16(a0h, bh[s], c0, 0, 0, 0);
            c1 = __builtin_amdgcn_mfma_f32_32x32x16_bf16(a1h, bh[s], c1, 0, 0, 0);
            c0 = __builtin_amdgcn_mfma_f32_32x32x16_bf16(a0h, bl[s], c0, 0, 0, 0);
            c1 = __builtin_amdgcn_mfma_f32_32x32x16_bf16(a1h, bl[s], c1, 0, 0, 0);
            c0 = __builtin_amdgcn_mfma_f32_32x32x16_bf16(a0l, bh[s], c0, 0, 0, 0);
            c1 = __builtin_amdgcn_mfma_f32_32x32x16_bf16(a1l, bh[s], c1, 0, 0, 0);
        }

        // stage C tile to LDS: msg[col][feat], feat XOR-swizzled (R8 pattern)
        const int sw = (col & 7) << 3;
        const int cb = col * 64;
#pragma unroll
        for (int rq = 0; rq < 4; ++rq) {
            const int fb = 8 * rq + 4 * hig;       // C row = (r&3)+8(r>>2)+4hig
            float4 v0 = {c0[4*rq], c0[4*rq+1], c0[4*rq+2], c0[4*rq+3]};
            float4 v1 = {c1[4*rq], c1[4*rq+1], c1[4*rq+2], c1[4*rq+3]};
            *(float4*)&msgw[cb + (fb ^ sw)] = v0;
            *(float4*)&msgw[cb + ((fb + 32) ^ sw)] = v1;
        }
        asm volatile("s_waitcnt lgkmcnt(0)" ::: "memory");

        // coalesced store-out: lanes 0-15 -> one node-row's 256B chunk
#pragma unroll
        for (int i = 0; i < 8; ++i) {
            const int idx = i * 64 + lane;
            const int row = idx >> 4, quad = idx & 15;
            const int qs = (row & 7) << 3;
            const float4 vv = *(const float4*)&msgw[row * 64 + ((quad * 4) ^ qs)];
            *(float4*)&Tb[(long)row * 1024 + c * 64 + quad * 4] = vv;
        }
        asm volatile("s_waitcnt lgkmcnt(0)" ::: "memory");
    }
}

// ---------------- streaming gather-aggregate + residual + LN partials -------
// Block = 64-dst tile; wave w owns dsts [16w,16w+16); lane = (dl, fq).
// 4-edge unrolled gather (16 independent 16B loads in flight per lane).
__global__ __launch_bounds__(256, 4)
void k_agg2(const float* __restrict__ T, const float* __restrict__ hres,
            const int* __restrict__ elist, const int* __restrict__ seg,
            float* __restrict__ outb, float* __restrict__ pbuf)
{
    __shared__ float red[2][4][64];
    const int tid = threadIdx.x;
    const int w = tid >> 6, lane = tid & 63;
    const int dl = lane >> 2, fq = lane & 3;
    const int tile = blockIdx.x;
    const int gd = tile * 64 + w * 16 + dl;

    float4 a0 = {0,0,0,0}, a1 = a0, a2 = a0, a3 = a0;

    if (gd < N_NODESC) {
        const int p0 = seg[gd * 16];
        const int p1 = seg[gd * 16 + 16];
        const float* __restrict__ Tf = T + 16 * fq;
        int p = p0;
        for (; p + 4 <= p1; p += 4) {
            const long t0 = (long)elist[p] * 64;
            const long t1 = (long)elist[p + 1] * 64;
            const long t2 = (long)elist[p + 2] * 64;
            const long t3 = (long)elist[p + 3] * 64;
            const float4 u00 = *(const float4*)&Tf[t0 + 0];
            const float4 u01 = *(const float4*)&Tf[t0 + 4];
            const float4 u02 = *(const float4*)&Tf[t0 + 8];
            const float4 u03 = *(const float4*)&Tf[t0 + 12];
            const float4 u10 = *(const float4*)&Tf[t1 + 0];
            const float4 u11 = *(const float4*)&Tf[t1 + 4];
            const float4 u12 = *(const float4*)&Tf[t1 + 8];
            const float4 u13 = *(const float4*)&Tf[t1 + 12];
            const float4 u20 = *(const float4*)&Tf[t2 + 0];
            const float4 u21 = *(const float4*)&Tf[t2 + 4];
            const float4 u22 = *(const float4*)&Tf[t2 + 8];
            const float4 u23 = *(const float4*)&Tf[t2 + 12];
            const float4 u30 = *(const float4*)&Tf[t3 + 0];
            const float4 u31 = *(const float4*)&Tf[t3 + 4];
            const float4 u32 = *(const float4*)&Tf[t3 + 8];
            const float4 u33 = *(const float4*)&Tf[t3 + 12];
            a0.x += u00.x + u10.x + u20.x + u30.x;
            a0.y += u00.y + u10.y + u20.y + u30.y;
            a0.z += u00.z + u10.z + u20.z + u30.z;
            a0.w += u00.w + u10.w + u20.w + u30.w;
            a1.x += u01.x + u11.x + u21.x + u31.x;
            a1.y += u01.y + u11.y + u21.y + u31.y;
            a1.z += u01.z + u11.z + u21.z + u31.z;
            a1.w += u01.w + u11.w + u21.w + u31.w;
            a2.x += u02.x + u12.x + u22.x + u32.x;
            a2.y += u02.y + u12.y + u22.y + u32.y;
            a2.z += u02.z + u12.z + u22.z + u32.z;
            a2.w += u02.w + u12.w + u22.w + u32.w;
            a3.x += u03.x + u13.x + u23.x + u33.x;
            a3.y += u03.y + u13.y + u23.y + u33.y;
            a3.z += u03.z + u13.z + u23.z + u33.z;
            a3.w += u03.w + u13.w + u23.w + u33.w;
        }
        for (; p < p1; ++p) {
            const long t0 = (long)elist[p] * 64;
            const float4 u0 = *(const float4*)&Tf[t0 + 0];
            const float4 u1 = *(const float4*)&Tf[t0 + 4];
            const float4 u2 = *(const float4*)&Tf[t0 + 8];
            const float4 u3 = *(const float4*)&Tf[t0 + 12];
            a0.x += u0.x; a0.y += u0.y; a0.z += u0.z; a0.w += u0.w;
            a1.x += u1.x; a1.y += u1.y; a1.z += u1.z; a1.w += u1.w;
            a2.x += u2.x; a2.y += u2.y; a2.z += u2.z; a2.w += u2.w;
            a3.x += u3.x; a3.y += u3.y; a3.z += u3.z; a3.w += u3.w;
        }
    }

    // ---- epilogue (R8 verbatim): residual + store + LN partials ----
    float4 v[4] = {a0, a1, a2, a3};
    if (gd < N_NODESC) {
        const float4* __restrict__ hr = (const float4*)(hres + (long)gd * 64 + 16 * fq);
        float4* __restrict__ ob = (float4*)(outb + (long)gd * 64 + 16 * fq);
#pragma unroll
        for (int u = 0; u < 4; ++u) {
            const float4 r = hr[u];
            v[u].x += r.x; v[u].y += r.y; v[u].z += r.z; v[u].w += r.w;
            ob[u] = v[u];
        }
    } else {
#pragma unroll
        for (int u = 0; u < 4; ++u) v[u] = make_float4(0.f, 0.f, 0.f, 0.f);
    }
    float s1[16], s2[16];
#pragma unroll
    for (int u = 0; u < 4; ++u) {
        s1[4*u+0] = v[u].x; s2[4*u+0] = v[u].x * v[u].x;
        s1[4*u+1] = v[u].y; s2[4*u+1] = v[u].y * v[u].y;
        s1[4*u+2] = v[u].z; s2[4*u+2] = v[u].z * v[u].z;
        s1[4*u+3] = v[u].w; s2[4*u+3] = v[u].w * v[u].w;
    }
#pragma unroll
    for (int j = 0; j < 16; ++j) {
        s1[j] += __shfl_xor(s1[j], 4);  s2[j] += __shfl_xor(s2[j], 4);
        s1[j] += __shfl_xor(s1[j], 8);  s2[j] += __shfl_xor(s2[j], 8);
        s1[j] += __shfl_xor(s1[j], 16); s2[j] += __shfl_xor(s2[j], 16);
        s1[j] += __shfl_xor(s1[j], 32); s2[j] += __shfl_xor(s2[j], 32);
    }
    if (dl == 0) {
#pragma unroll
        for (int j = 0; j < 16; ++j) {
            red[0][w][16 * fq + j] = s1[j];
            red[1][w][16 * fq + j] = s2[j];
        }
    }
    __syncthreads();
    if (tid < 64) {
        const float t1 = red[0][0][tid] + red[0][1][tid] + red[0][2][tid] + red[0][3][tid];
        const float t2 = red[1][0][tid] + red[1][1][tid] + red[1][2][tid] + red[1][3][tid];
        pbuf[tile * 128 + tid] = t1;
        pbuf[tile * 128 + 64 + tid] = t2;
    }
}

// ---------------- reduce LN partials -> scale/shift ----------------
__global__ __launch_bounds__(1024)
void k_norm2(const float* __restrict__ pbuf, const float* __restrict__ g,
             const float* __restrict__ be, float* __restrict__ scale,
             float* __restrict__ shift)
{
    __shared__ float s[1024];
    const int t = threadIdx.x, j = t & 127, gg = t >> 7;
    float a = 0.f;
    for (int b = gg; b < NTILE; b += 8) a += pbuf[b * 128 + j];
    s[t] = a;
    __syncthreads();
    if (t < 128) {
        float tot = 0.f;
#pragma unroll
        for (int k = 0; k < 8; ++k) tot += s[j + 128 * k];
        s[t] = tot;
    }
    __syncthreads();
    if (t < 64) {
        const double mu  = (double)s[t] / (double)N_NODESC;
        const double var = (double)s[64 + t] / (double)N_NODESC - mu * mu;
        const double sc  = (double)g[t] / sqrt(var + (double)EPSF);
        scale[t] = (float)sc;
        shift[t] = (float)((double)be[t] - mu * sc);
    }
}

// ---------------- final projection (LN apply fused) ----------------
__global__ __launch_bounds__(256)
void k_out(const float* __restrict__ outb, const float* __restrict__ scale,
           const float* __restrict__ shift, const float* __restrict__ resW,
           const float* __restrict__ resb, float* __restrict__ out)
{
    const int n = blockIdx.x * 256 + threadIdx.x;
    if (n >= N_NODESC) return;
    float a0 = resb[0], a1 = resb[1];
    const float* __restrict__ r = outb + (long)n * 64;
#pragma unroll 8
    for (int e = 0; e < 64; ++e) {
        const float v = fmaxf(r[e] * scale[e] + shift[e], 0.f);
        a0 += v * resW[2 * e];
        a1 += v * resW[2 * e + 1];
    }
    out[2 * n] = a0;
    out[2 * n + 1] = a1;
}

extern "C" void kernel_launch(void* const* d_in, const int* in_sizes, int n_in,
                              void* d_out, int out_size, void* d_ws, size_t ws_size,
                              hipStream_t stream)
{
    const float* x      = (const float*)d_in[0];
    const float* M      = (const float*)d_in[1];
    const int*   src    = (const int*)d_in[2];
    const int*   dst    = (const int*)d_in[3];
    const int*   labels = (const int*)d_in[4];
    const int*   bidx   = (const int*)d_in[5];
    const float* resW   = (const float*)d_in[18];
    const float* resb   = (const float*)d_in[19];
    float* out = (float*)d_out;

    char* ws = (char*)d_ws;
    float*  scale = (float*)(ws + WS_SCALE);
    float*  shift = (float*)(ws + WS_SHIFT);
    int*    bsum  = (int*)(ws + WS_BSUM);
    float*  pbuf  = (float*)(ws + WS_PBUF);
    int*    hist  = (int*)(ws + WS_HIST);
    int*    fill  = (int*)(ws + WS_FILL);
    int*    seg   = (int*)(ws + WS_SEG);
    int*    elist = (int*)(ws + WS_ELIST);
    ushort* Ahi   = (ushort*)(ws + WS_AHI);
    ushort* Alo   = (ushort*)(ws + WS_ALO);
    ushort* hhi   = (ushort*)(ws + WS_HHI);
    ushort* hlo   = (ushort*)(ws + WS_HLO);
    float*  hB    = (float*)(ws + WS_HB);
    float*  outb  = (float*)(ws + WS_OUTB);
    float*  T     = (float*)(ws + WS_T);

    // ---- preprocessing (graph + M constant across layers) ----
    hipMemsetAsync(hist, 0, 2 * (size_t)NKEYS * sizeof(int), stream);  // hist + fill
    k_hist<<<NEBLK, 256, 0, stream>>>(src, dst, labels, bidx, hist);
    k_bsum<<<NHBLK, 256, 0, stream>>>(hist, bsum);
    k_bscan2<<<1, 1024, 0, stream>>>(bsum);
    k_escan2<<<NHBLK, 256, 0, stream>>>(hist, bsum, seg);
    k_scat<<<NEBLK, 256, 0, stream>>>(src, dst, labels, bidx, seg, fill, elist);
    k_mfrag<<<16, 256, 0, stream>>>(M, Ahi, Alo);

    for (int l = 0; l < 3; ++l) {
        const float* W  = (const float*)d_in[6 + 4 * l];
        const float* b  = (const float*)d_in[7 + 4 * l];
        const float* g  = (const float*)d_in[8 + 4 * l];
        const float* be = (const float*)d_in[9 + 4 * l];

        if (l == 0) {
            k_h<<<3125, 256, 0, stream>>>(x, W, b, hB, hhi, hlo, 128);
        } else {
            k_happly<<<(N_NODESC + 15) / 16, 256, 0, stream>>>(outb, scale, shift,
                                                               W, b, hB, hhi, hlo);
        }
        k_T<<<NTBLK, 256, 0, stream>>>(hhi, hlo, Ahi, Alo, T);
        k_agg2<<<NTILE, 256, 0, stream>>>(T, hB, elist, seg, outb, pbuf);
        k_norm2<<<1, 1024, 0, stream>>>(pbuf, g, be, scale, shift);
    }
    k_out<<<(N_NODESC + 255) / 256, 256, 0, stream>>>(outb, scale, shift, resW, resb, out);
    (void)in_sizes; (void)n_in; (void)out_size; (void)ws_size;
}

// Round 18
// 579.981 us; speedup vs baseline: 1.8218x; 1.0617x over previous
//
#include <hip/hip_runtime.h>

// Problem constants
#define N_NODESC 50000
#define N_EDGESC 800000
#define EPSF 1e-5f
#define NTILE 782                   // ceil(50000/64)  (agg tiles)
#define NTBLK 1563                  // ceil(50000/32)  (k_T9 blocks)
#define NSLOT 9                     // 8 non-identity combos + 1 h slot
#define TROW  576                   // 9*64 floats per T9 row
#define NKEY9 450000                // 50000*9
#define NKPAD9 450048               // 1758*256
#define NHBLK9 1758
#define NEBLK 3125                  // 800000/256

typedef __attribute__((ext_vector_type(8))) short short8;
typedef __attribute__((ext_vector_type(16))) float f32x16;

// ---- ws layout (bytes), total ~163 MB ----
#define WS_SCALE 0
#define WS_SHIFT 256
#define WS_BSUM  512                  // 1758 int
#define WS_PBUF  8704                 // 782*128 f32 -> ends 409088
#define WS_HIST  409600               // 450048 int
#define WS_FILL  2209792              // 450048 int (contiguous after hist)
#define WS_SEG   4009984              // 450049 int -> pad to 5810432
#define WS_ELIST 5810432              // 800000 int (float-offset into T9)
#define WS_GHI   9010432              // 147456 B (9*2*8*64*8 ushort max)
#define WS_GLO   9157888              // 147456 B
#define WS_BVEC  9305344              // 9*64 f32 -> pad to 9308160
#define WS_ACTHI 9308160              // 50016*128 ushort (max F)
#define WS_ACTLO 22112256             // 50016*128 ushort
#define WS_OUTB  34916352             // 50000*64 f32
#define WS_T9    47716352             // 50016*576 f32 = 115.2 MB

__device__ __forceinline__ ushort bf_hi(float v) {
    return (ushort)(__float_as_uint(v) >> 16);
}
__device__ __forceinline__ ushort bf_lo(float v) {
    const unsigned b = __float_as_uint(v);
    const float lof = v - __uint_as_float(b & 0xFFFF0000u);
    return (ushort)(__float_as_uint(lof) >> 16);
}

// slot: identity combos (label_dst==label_src) -> 8; else c-4 in [0,8)
__device__ __forceinline__ int edge_slot(int ld, int ls, int bx) {
    return (ld == ls) ? 8 : ((ld * 2 + ls) * 4 + bx - 4);
}

// ---------------- histogram over (dst, slot) ----------------
__global__ __launch_bounds__(256)
void k_hist9(const int* __restrict__ src, const int* __restrict__ dst,
             const int* __restrict__ labels, const int* __restrict__ bidx,
             int* __restrict__ hist)
{
    const int e = blockIdx.x * 256 + threadIdx.x;
    if (e >= N_EDGESC) return;
    const int s = src[e], d = dst[e];
    const int slot = edge_slot(labels[d], labels[s], bidx[e]);
    atomicAdd(&hist[d * 9 + slot], 1);
}

// ---------------- 3-level scan ----------------
__global__ __launch_bounds__(256)
void k_bsum(const int* __restrict__ hist, int* __restrict__ bsum)
{
    __shared__ int s[256];
    const int i = blockIdx.x * 256 + threadIdx.x;
    s[threadIdx.x] = hist[i];
    __syncthreads();
    for (int off = 128; off > 0; off >>= 1) {
        if (threadIdx.x < off) s[threadIdx.x] += s[threadIdx.x + off];
        __syncthreads();
    }
    if (threadIdx.x == 0) bsum[blockIdx.x] = s[0];
}

__global__ __launch_bounds__(1024)
void k_bscan2(int* __restrict__ bsum)   // in-place exclusive scan of NHBLK9
{
    __shared__ int s[1024];
    const int t = threadIdx.x;
    int v[4]; int tot = 0;
#pragma unroll
    for (int j = 0; j < 4; ++j) {
        const int i = t * 4 + j;
        v[j] = (i < NHBLK9) ? bsum[i] : 0;
        tot += v[j];
    }
    s[t] = tot; __syncthreads();
    for (int off = 1; off < 1024; off <<= 1) {
        const int x = (t >= off) ? s[t - off] : 0;
        __syncthreads();
        s[t] += x;
        __syncthreads();
    }
    int base = s[t] - tot;
#pragma unroll
    for (int j = 0; j < 4; ++j) {
        const int i = t * 4 + j;
        if (i < NHBLK9) bsum[i] = base;
        base += v[j];
    }
}

__global__ __launch_bounds__(256)
void k_escan2(const int* __restrict__ hist, const int* __restrict__ bsum,
              int* __restrict__ seg)
{
    __shared__ int s[256];
    const int t = threadIdx.x;
    const int i = blockIdx.x * 256 + t;
    const int v = hist[i];
    s[t] = v; __syncthreads();
    for (int off = 1; off < 256; off <<= 1) {
        const int x = (t >= off) ? s[t - off] : 0;
        __syncthreads();
        s[t] += x;
        __syncthreads();
    }
    seg[i] = bsum[blockIdx.x] + s[t] - v;
}

__global__ __launch_bounds__(256)
void k_scat9(const int* __restrict__ src, const int* __restrict__ dst,
             const int* __restrict__ labels, const int* __restrict__ bidx,
             const int* __restrict__ seg, int* __restrict__ fill,
             int* __restrict__ elist)
{
    const int e = blockIdx.x * 256 + threadIdx.x;
    if (e >= N_EDGESC) return;
    const int s = src[e], d = dst[e];
    const int slot = edge_slot(labels[d], labels[s], bidx[e]);
    const int k = d * 9 + slot;
    const int pos = seg[k] + atomicAdd(&fill[k], 1);
    elist[pos] = s * TROW + slot * 64;     // float offset into T9
}

// ---- per-layer: G_slot = M_{slot+4} @ W^T (slot<8), W^T (slot 8); + bias ----
// Fragment layout identical to verified k_mfrag: elem = G[(lane&31)+32t][16s+8hig+j]
__global__ __launch_bounds__(256)
void k_gfrag(const float* __restrict__ M, const float* __restrict__ W,
             const float* __restrict__ b, ushort* __restrict__ Ghi,
             ushort* __restrict__ Glo, float* __restrict__ bvec, const int F)
{
    __shared__ float Ml[4096];
    const int slot = blockIdx.x;
    const int tid = threadIdx.x;
    const int KS = F >> 4;
    if (slot < 8) {
        const float* __restrict__ Mc = M + (slot + 4) * 4096;
        for (int i = tid; i < 4096; i += 256) Ml[i] = Mc[i];
    }
    __syncthreads();
    if (tid < 64) {
        float acc;
        if (slot < 8) {
            acc = 0.f;
            for (int e = 0; e < 64; ++e) acc += Ml[tid * 64 + e] * b[e];
        } else acc = b[tid];
        bvec[slot * 64 + tid] = acc;
    }
    const int total = 2 * KS * 512;          // t * s * lane * j
    for (int u = tid; u < total; u += 256) {
        const int j = u & 7;
        const int lane = (u >> 3) & 63;
        const int s = (u >> 9) % KS;
        const int t = u / (KS * 512);
        const int r = (lane & 31) + 32 * t;
        const int f = 16 * s + 8 * (lane >> 5) + j;
        float g;
        if (slot < 8) {
            g = 0.f;
            const float* __restrict__ wr = W + f * 64;
            const float* __restrict__ mr = Ml + r * 64;
            for (int e = 0; e < 64; ++e) g += mr[e] * wr[e];
        } else {
            g = W[f * 64 + r];
        }
        const int fid = ((slot * 2 + t) * KS + s) * 64 + lane;
        Ghi[fid * 8 + j] = bf_hi(g);
        Glo[fid * 8 + j] = bf_lo(g);
    }
}

// ---------------- act split: layer 0 (x direct) ----------------
__global__ __launch_bounds__(256)
void k_actx(const float* __restrict__ x, ushort* __restrict__ ahi,
            ushort* __restrict__ alo)
{
    const int t = blockIdx.x * 256 + threadIdx.x;
    if (t * 4 >= N_NODESC * 128) return;
    const float4 v = *(const float4*)&x[t * 4];
    ushort4 h4, l4;
    h4.x = bf_hi(v.x); h4.y = bf_hi(v.y); h4.z = bf_hi(v.z); h4.w = bf_hi(v.w);
    l4.x = bf_lo(v.x); l4.y = bf_lo(v.y); l4.z = bf_lo(v.z); l4.w = bf_lo(v.w);
    *(ushort4*)&ahi[t * 4] = h4;
    *(ushort4*)&alo[t * 4] = l4;
}

// ---------------- act: LN-apply + relu + split (layers 1,2) ----------------
__global__ __launch_bounds__(256)
void k_act(const float* __restrict__ outb, const float* __restrict__ scale,
           const float* __restrict__ shift, ushort* __restrict__ ahi,
           ushort* __restrict__ alo)
{
    const int t = blockIdx.x * 256 + threadIdx.x;
    if (t * 4 >= N_NODESC * 64) return;
    const int e0 = (t * 4) & 63;
    const float4 v = *(const float4*)&outb[t * 4];
    const float a0 = fmaxf(v.x * scale[e0] + shift[e0], 0.f);
    const float a1 = fmaxf(v.y * scale[e0 + 1] + shift[e0 + 1], 0.f);
    const float a2 = fmaxf(v.z * scale[e0 + 2] + shift[e0 + 2], 0.f);
    const float a3 = fmaxf(v.w * scale[e0 + 3] + shift[e0 + 3], 0.f);
    ushort4 h4, l4;
    h4.x = bf_hi(a0); h4.y = bf_hi(a1); h4.z = bf_hi(a2); h4.w = bf_hi(a3);
    l4.x = bf_lo(a0); l4.y = bf_lo(a1); l4.z = bf_lo(a2); l4.w = bf_lo(a3);
    *(ushort4*)&ahi[t * 4] = h4;
    *(ushort4*)&alo[t * 4] = l4;
}

// ---------------- 9-slot transform table (fused W + M GEMM) ----------------
// Block = 32 nodes; wave w handles slots w, w+4, (w==0: 8). C init = bias.
// Slot 8 output IS h (residual). Runtime KS keeps one B-set live (no spill).
__global__ __launch_bounds__(256, 3)
void k_T9(const ushort* __restrict__ ahi, const ushort* __restrict__ alo,
          const ushort* __restrict__ Ghi, const ushort* __restrict__ Glo,
          const float* __restrict__ bvec, float* __restrict__ T9,
          const int KS, const int F)
{
    __shared__ float msg[4][2048];        // per-wave 32 nodes x 64 feats (32 KB)
    const int tid = threadIdx.x;
    const int w = tid >> 6, lane = tid & 63;
    const int col = lane & 31, hig = lane >> 5;
    const int node = blockIdx.x * 32 + col;
    const ushort* __restrict__ rh = ahi + (long)node * F + hig * 8;
    const ushort* __restrict__ rl = alo + (long)node * F + hig * 8;
    float* __restrict__ msgw = msg[w];
    float* __restrict__ Tb = T9 + (long)blockIdx.x * 32 * TROW;

    for (int slot = w; slot < 9; slot += 4) {
        f32x16 c0, c1;
#pragma unroll
        for (int r = 0; r < 16; ++r) {
            const int fp = (r & 3) + 8 * (r >> 2) + 4 * hig;
            c0[r] = bvec[slot * 64 + fp];
            c1[r] = bvec[slot * 64 + fp + 32];
        }
        for (int s = 0; s < KS; ++s) {
            const int fid0 = ((slot * 2 + 0) * KS + s) * 64 + lane;
            const int fid1 = ((slot * 2 + 1) * KS + s) * 64 + lane;
            const short8 a0h = *(const short8*)&Ghi[fid0 * 8];
            const short8 a1h = *(const short8*)&Ghi[fid1 * 8];
            const short8 a0l = *(const short8*)&Glo[fid0 * 8];
            const short8 a1l = *(const short8*)&Glo[fid1 * 8];
            const short8 bh = *(const short8*)&rh[s * 16];
            const short8 bl = *(const short8*)&rl[s * 16];
            c0 = __builtin_amdgcn_mfma_f32_32x32x16_bf16(a0h, bh, c0, 0, 0, 0);
            c1 = __builtin_amdgcn_mfma_f32_32x32x16_bf16(a1h, bh, c1, 0, 0, 0);
            c0 = __builtin_amdgcn_mfma_f32_32x32x16_bf16(a0h, bl, c0, 0, 0, 0);
            c1 = __builtin_amdgcn_mfma_f32_32x32x16_bf16(a1h, bl, c1, 0, 0, 0);
            c0 = __builtin_amdgcn_mfma_f32_32x32x16_bf16(a0l, bh, c0, 0, 0, 0);
            c1 = __builtin_amdgcn_mfma_f32_32x32x16_bf16(a1l, bh, c1, 0, 0, 0);
        }

        // stage C tile to LDS (verified swizzle), then coalesced store-out
        const int sw = (col & 7) << 3;
        const int cb = col * 64;
#pragma unroll
        for (int rq = 0; rq < 4; ++rq) {
            const int fb = 8 * rq + 4 * hig;
            float4 v0 = {c0[4*rq], c0[4*rq+1], c0[4*rq+2], c0[4*rq+3]};
            float4 v1 = {c1[4*rq], c1[4*rq+1], c1[4*rq+2], c1[4*rq+3]};
            *(float4*)&msgw[cb + (fb ^ sw)] = v0;
            *(float4*)&msgw[cb + ((fb + 32) ^ sw)] = v1;
        }
        asm volatile("s_waitcnt lgkmcnt(0)" ::: "memory");
#pragma unroll
        for (int i = 0; i < 8; ++i) {
            const int idx = i * 64 + lane;
            const int row = idx >> 4, quad = idx & 15;
            const int qs = (row & 7) << 3;
            const float4 vv = *(const float4*)&msgw[row * 64 + ((quad * 4) ^ qs)];
            *(float4*)&Tb[(long)row * TROW + slot * 64 + quad * 4] = vv;
        }
        asm volatile("s_waitcnt lgkmcnt(0)" ::: "memory");
    }
}

// ---------------- gather-aggregate + residual(T9 slot 8) + LN partials ------
__global__ __launch_bounds__(256, 4)
void k_agg2(const float* __restrict__ T9, const int* __restrict__ elist,
            const int* __restrict__ seg, float* __restrict__ outb,
            float* __restrict__ pbuf)
{
    __shared__ float red[2][4][64];
    const int tid = threadIdx.x;
    const int w = tid >> 6, lane = tid & 63;
    const int dl = lane >> 2, fq = lane & 3;
    const int tile = blockIdx.x;
    const int gd = tile * 64 + w * 16 + dl;

    float4 a0 = {0,0,0,0}, a1 = a0, a2 = a0, a3 = a0;

    if (gd < N_NODESC) {
        const int p0 = seg[gd * 9];
        const int p1 = seg[gd * 9 + 9];
        const float* __restrict__ Tf = T9 + 16 * fq;
        int p = p0;
        for (; p + 4 <= p1; p += 4) {
            const long t0 = (long)elist[p];
            const long t1 = (long)elist[p + 1];
            const long t2 = (long)elist[p + 2];
            const long t3 = (long)elist[p + 3];
            const float4 u00 = *(const float4*)&Tf[t0 + 0];
            const float4 u01 = *(const float4*)&Tf[t0 + 4];
            const float4 u02 = *(const float4*)&Tf[t0 + 8];
            const float4 u03 = *(const float4*)&Tf[t0 + 12];
            const float4 u10 = *(const float4*)&Tf[t1 + 0];
            const float4 u11 = *(const float4*)&Tf[t1 + 4];
            const float4 u12 = *(const float4*)&Tf[t1 + 8];
            const float4 u13 = *(const float4*)&Tf[t1 + 12];
            const float4 u20 = *(const float4*)&Tf[t2 + 0];
            const float4 u21 = *(const float4*)&Tf[t2 + 4];
            const float4 u22 = *(const float4*)&Tf[t2 + 8];
            const float4 u23 = *(const float4*)&Tf[t2 + 12];
            const float4 u30 = *(const float4*)&Tf[t3 + 0];
            const float4 u31 = *(const float4*)&Tf[t3 + 4];
            const float4 u32 = *(const float4*)&Tf[t3 + 8];
            const float4 u33 = *(const float4*)&Tf[t3 + 12];
            a0.x += u00.x + u10.x + u20.x + u30.x;
            a0.y += u00.y + u10.y + u20.y + u30.y;
            a0.z += u00.z + u10.z + u20.z + u30.z;
            a0.w += u00.w + u10.w + u20.w + u30.w;
            a1.x += u01.x + u11.x + u21.x + u31.x;
            a1.y += u01.y + u11.y + u21.y + u31.y;
            a1.z += u01.z + u11.z + u21.z + u31.z;
            a1.w += u01.w + u11.w + u21.w + u31.w;
            a2.x += u02.x + u12.x + u22.x + u32.x;
            a2.y += u02.y + u12.y + u22.y + u32.y;
            a2.z += u02.z + u12.z + u22.z + u32.z;
            a2.w += u02.w + u12.w + u22.w + u32.w;
            a3.x += u03.x + u13.x + u23.x + u33.x;
            a3.y += u03.y + u13.y + u23.y + u33.y;
            a3.z += u03.z + u13.z + u23.z + u33.z;
            a3.w += u03.w + u13.w + u23.w + u33.w;
        }
        for (; p < p1; ++p) {
            const long t0 = (long)elist[p];
            const float4 u0 = *(const float4*)&Tf[t0 + 0];
            const float4 u1 = *(const float4*)&Tf[t0 + 4];
            const float4 u2 = *(const float4*)&Tf[t0 + 8];
            const float4 u3 = *(const float4*)&Tf[t0 + 12];
            a0.x += u0.x; a0.y += u0.y; a0.z += u0.z; a0.w += u0.w;
            a1.x += u1.x; a1.y += u1.y; a1.z += u1.z; a1.w += u1.w;
            a2.x += u2.x; a2.y += u2.y; a2.z += u2.z; a2.w += u2.w;
            a3.x += u3.x; a3.y += u3.y; a3.z += u3.z; a3.w += u3.w;
        }
    }

    // ---- epilogue: residual (T9 slot 8 = h) + store + LN partials ----
    float4 v[4] = {a0, a1, a2, a3};
    if (gd < N_NODESC) {
        const float4* __restrict__ hr =
            (const float4*)(T9 + (long)gd * TROW + 512 + 16 * fq);
        float4* __restrict__ ob = (float4*)(outb + (long)gd * 64 + 16 * fq);
#pragma unroll
        for (int u = 0; u < 4; ++u) {
            const float4 r = hr[u];
            v[u].x += r.x; v[u].y += r.y; v[u].z += r.z; v[u].w += r.w;
            ob[u] = v[u];
        }
    } else {
#pragma unroll
        for (int u = 0; u < 4; ++u) v[u] = make_float4(0.f, 0.f, 0.f, 0.f);
    }
    float s1[16], s2[16];
#pragma unroll
    for (int u = 0; u < 4; ++u) {
        s1[4*u+0] = v[u].x; s2[4*u+0] = v[u].x * v[u].x;
        s1[4*u+1] = v[u].y; s2[4*u+1] = v[u].y * v[u].y;
        s1[4*u+2] = v[u].z; s2[4*u+2] = v[u].z * v[u].z;
        s1[4*u+3] = v[u].w; s2[4*u+3] = v[u].w * v[u].w;
    }
#pragma unroll
    for (int j = 0; j < 16; ++j) {
        s1[j] += __shfl_xor(s1[j], 4);  s2[j] += __shfl_xor(s2[j], 4);
        s1[j] += __shfl_xor(s1[j], 8);  s2[j] += __shfl_xor(s2[j], 8);
        s1[j] += __shfl_xor(s1[j], 16); s2[j] += __shfl_xor(s2[j], 16);
        s1[j] += __shfl_xor(s1[j], 32); s2[j] += __shfl_xor(s2[j], 32);
    }
    if (dl == 0) {
#pragma unroll
        for (int j = 0; j < 16; ++j) {
            red[0][w][16 * fq + j] = s1[j];
            red[1][w][16 * fq + j] = s2[j];
        }
    }
    __syncthreads();
    if (tid < 64) {
        const float t1 = red[0][0][tid] + red[0][1][tid] + red[0][2][tid] + red[0][3][tid];
        const float t2 = red[1][0][tid] + red[1][1][tid] + red[1][2][tid] + red[1][3][tid];
        pbuf[tile * 128 + tid] = t1;
        pbuf[tile * 128 + 64 + tid] = t2;
    }
}

// ---------------- reduce LN partials -> scale/shift ----------------
__global__ __launch_bounds__(1024)
void k_norm2(const float* __restrict__ pbuf, const float* __restrict__ g,
             const float* __restrict__ be, float* __restrict__ scale,
             float* __restrict__ shift)
{
    __shared__ float s[1024];
    const int t = threadIdx.x, j = t & 127, gg = t >> 7;
    float a = 0.f;
    for (int b = gg; b < NTILE; b += 8) a += pbuf[b * 128 + j];
    s[t] = a;
    __syncthreads();
    if (t < 128) {
        float tot = 0.f;
#pragma unroll
        for (int k = 0; k < 8; ++k) tot += s[j + 128 * k];
        s[t] = tot;
    }
    __syncthreads();
    if (t < 64) {
        const double mu  = (double)s[t] / (double)N_NODESC;
        const double var = (double)s[64 + t] / (double)N_NODESC - mu * mu;
        const double sc  = (double)g[t] / sqrt(var + (double)EPSF);
        scale[t] = (float)sc;
        shift[t] = (float)((double)be[t] - mu * sc);
    }
}

// ---------------- final projection (LN apply fused) ----------------
__global__ __launch_bounds__(256)
void k_out(const float* __restrict__ outb, const float* __restrict__ scale,
           const float* __restrict__ shift, const float* __restrict__ resW,
           const float* __restrict__ resb, float* __restrict__ out)
{
    const int n = blockIdx.x * 256 + threadIdx.x;
    if (n >= N_NODESC) return;
    float a0 = resb[0], a1 = resb[1];
    const float* __restrict__ r = outb + (long)n * 64;
#pragma unroll 8
    for (int e = 0; e < 64; ++e) {
        const float v = fmaxf(r[e] * scale[e] + shift[e], 0.f);
        a0 += v * resW[2 * e];
        a1 += v * resW[2 * e + 1];
    }
    out[2 * n] = a0;
    out[2 * n + 1] = a1;
}

extern "C" void kernel_launch(void* const* d_in, const int* in_sizes, int n_in,
                              void* d_out, int out_size, void* d_ws, size_t ws_size,
                              hipStream_t stream)
{
    const float* x      = (const float*)d_in[0];
    const float* M      = (const float*)d_in[1];
    const int*   src    = (const int*)d_in[2];
    const int*   dst    = (const int*)d_in[3];
    const int*   labels = (const int*)d_in[4];
    const int*   bidx   = (const int*)d_in[5];
    const float* resW   = (const float*)d_in[18];
    const float* resb   = (const float*)d_in[19];
    float* out = (float*)d_out;

    char* ws = (char*)d_ws;
    float*  scale = (float*)(ws + WS_SCALE);
    float*  shift = (float*)(ws + WS_SHIFT);
    int*    bsum  = (int*)(ws + WS_BSUM);
    float*  pbuf  = (float*)(ws + WS_PBUF);
    int*    hist  = (int*)(ws + WS_HIST);
    int*    fill  = (int*)(ws + WS_FILL);
    int*    seg   = (int*)(ws + WS_SEG);
    int*    elist = (int*)(ws + WS_ELIST);
    ushort* Ghi   = (ushort*)(ws + WS_GHI);
    ushort* Glo   = (ushort*)(ws + WS_GLO);
    float*  bvec  = (float*)(ws + WS_BVEC);
    ushort* ahi   = (ushort*)(ws + WS_ACTHI);
    ushort* alo   = (ushort*)(ws + WS_ACTLO);
    float*  outb  = (float*)(ws + WS_OUTB);
    float*  T9    = (float*)(ws + WS_T9);

    // ---- preprocessing (graph constant across layers) ----
    hipMemsetAsync(hist, 0, 2 * (size_t)NKPAD9 * sizeof(int), stream);  // hist+fill
    k_hist9<<<NEBLK, 256, 0, stream>>>(src, dst, labels, bidx, hist);
    k_bsum<<<NHBLK9, 256, 0, stream>>>(hist, bsum);
    k_bscan2<<<1, 1024, 0, stream>>>(bsum);
    k_escan2<<<NHBLK9, 256, 0, stream>>>(hist, bsum, seg);
    k_scat9<<<NEBLK, 256, 0, stream>>>(src, dst, labels, bidx, seg, fill, elist);

    for (int l = 0; l < 3; ++l) {
        const float* W  = (const float*)d_in[6 + 4 * l];
        const float* b  = (const float*)d_in[7 + 4 * l];
        const float* g  = (const float*)d_in[8 + 4 * l];
        const float* be = (const float*)d_in[9 + 4 * l];
        const int F = (l == 0) ? 128 : 64;

        k_gfrag<<<9, 256, 0, stream>>>(M, W, b, Ghi, Glo, bvec, F);
        if (l == 0) {
            k_actx<<<6250, 256, 0, stream>>>(x, ahi, alo);
        } else {
            k_act<<<3125, 256, 0, stream>>>(outb, scale, shift, ahi, alo);
        }
        k_T9<<<NTBLK, 256, 0, stream>>>(ahi, alo, Ghi, Glo, bvec, T9, F >> 4, F);
        k_agg2<<<NTILE, 256, 0, stream>>>(T9, elist, seg, outb, pbuf);
        k_norm2<<<1, 1024, 0, stream>>>(pbuf, g, be, scale, shift);
    }
    k_out<<<(N_NODESC + 255) / 256, 256, 0, stream>>>(outb, scale, shift, resW, resb, out);
    (void)in_sizes; (void)n_in; (void)out_size; (void)ws_size;
}

// Round 19
// 463.486 us; speedup vs baseline: 2.2797x; 1.2513x over previous
//
#include <hip/hip_runtime.h>

// Problem constants
#define N_NODESC 50000
#define N_EDGESC 800000
#define EPSF 1e-5f
#define NTILE 782                   // ceil(50000/64)  (agg tiles)
#define NTBLK 1563                  // ceil(50000/32)  (k_T9 blocks)
#define NSLOT 9                     // 8 non-identity combos + 1 h slot
#define TROW  576                   // 9*64 floats per T9 row
#define NKEY9 450000                // 50000*9
#define NKPAD9 450048               // 1758*256
#define NHBLK9 1758
#define NEBLK 3125                  // 800000/256
#define GCHUNK 32                   // k_gfrag parallel chunks per slot

typedef __attribute__((ext_vector_type(8))) short short8;
typedef __attribute__((ext_vector_type(16))) float f32x16;

// ---- ws layout (bytes), total ~163 MB ----
#define WS_SCALE 0
#define WS_SHIFT 256
#define WS_BSUM  512                  // 1758 int
#define WS_PBUF  8704                 // 782*128 f32 -> ends 409088
#define WS_HIST  409600               // 450048 int
#define WS_FILL  2209792              // 450048 int (contiguous after hist)
#define WS_SEG   4009984              // 450049 int -> pad to 5810432
#define WS_ELIST 5810432              // 800000 int (float-offset into T9)
#define WS_GHI   9010432              // 147456 B (9*2*8*64*8 ushort max)
#define WS_GLO   9157888              // 147456 B
#define WS_BVEC  9305344              // 9*64 f32 -> pad to 9308160
#define WS_ACTHI 9308160              // 50016*128 ushort (max F)
#define WS_ACTLO 22112256             // 50016*128 ushort
#define WS_OUTB  34916352             // 50000*64 f32
#define WS_T9    47716352             // 50016*576 f32 = 115.2 MB

__device__ __forceinline__ ushort bf_hi(float v) {
    return (ushort)(__float_as_uint(v) >> 16);
}
__device__ __forceinline__ ushort bf_lo(float v) {
    const unsigned b = __float_as_uint(v);
    const float lof = v - __uint_as_float(b & 0xFFFF0000u);
    return (ushort)(__float_as_uint(lof) >> 16);
}

// slot: identity combos (label_dst==label_src) -> 8; else c-4 in [0,8)
__device__ __forceinline__ int edge_slot(int ld, int ls, int bx) {
    return (ld == ls) ? 8 : ((ld * 2 + ls) * 4 + bx - 4);
}

// ---------------- histogram over (dst, slot) ----------------
__global__ __launch_bounds__(256)
void k_hist9(const int* __restrict__ src, const int* __restrict__ dst,
             const int* __restrict__ labels, const int* __restrict__ bidx,
             int* __restrict__ hist)
{
    const int e = blockIdx.x * 256 + threadIdx.x;
    if (e >= N_EDGESC) return;
    const int s = src[e], d = dst[e];
    const int slot = edge_slot(labels[d], labels[s], bidx[e]);
    atomicAdd(&hist[d * 9 + slot], 1);
}

// ---------------- 3-level scan ----------------
__global__ __launch_bounds__(256)
void k_bsum(const int* __restrict__ hist, int* __restrict__ bsum)
{
    __shared__ int s[256];
    const int i = blockIdx.x * 256 + threadIdx.x;
    s[threadIdx.x] = hist[i];
    __syncthreads();
    for (int off = 128; off > 0; off >>= 1) {
        if (threadIdx.x < off) s[threadIdx.x] += s[threadIdx.x + off];
        __syncthreads();
    }
    if (threadIdx.x == 0) bsum[blockIdx.x] = s[0];
}

__global__ __launch_bounds__(1024)
void k_bscan2(int* __restrict__ bsum)   // in-place exclusive scan of NHBLK9
{
    __shared__ int s[1024];
    const int t = threadIdx.x;
    int v[4]; int tot = 0;
#pragma unroll
    for (int j = 0; j < 4; ++j) {
        const int i = t * 4 + j;
        v[j] = (i < NHBLK9) ? bsum[i] : 0;
        tot += v[j];
    }
    s[t] = tot; __syncthreads();
    for (int off = 1; off < 1024; off <<= 1) {
        const int x = (t >= off) ? s[t - off] : 0;
        __syncthreads();
        s[t] += x;
        __syncthreads();
    }
    int base = s[t] - tot;
#pragma unroll
    for (int j = 0; j < 4; ++j) {
        const int i = t * 4 + j;
        if (i < NHBLK9) bsum[i] = base;
        base += v[j];
    }
}

__global__ __launch_bounds__(256)
void k_escan2(const int* __restrict__ hist, const int* __restrict__ bsum,
              int* __restrict__ seg)
{
    __shared__ int s[256];
    const int t = threadIdx.x;
    const int i = blockIdx.x * 256 + t;
    const int v = hist[i];
    s[t] = v; __syncthreads();
    for (int off = 1; off < 256; off <<= 1) {
        const int x = (t >= off) ? s[t - off] : 0;
        __syncthreads();
        s[t] += x;
        __syncthreads();
    }
    seg[i] = bsum[blockIdx.x] + s[t] - v;
}

__global__ __launch_bounds__(256)
void k_scat9(const int* __restrict__ src, const int* __restrict__ dst,
             const int* __restrict__ labels, const int* __restrict__ bidx,
             const int* __restrict__ seg, int* __restrict__ fill,
             int* __restrict__ elist)
{
    const int e = blockIdx.x * 256 + threadIdx.x;
    if (e >= N_EDGESC) return;
    const int s = src[e], d = dst[e];
    const int slot = edge_slot(labels[d], labels[s], bidx[e]);
    const int k = d * 9 + slot;
    const int pos = seg[k] + atomicAdd(&fill[k], 1);
    elist[pos] = s * TROW + slot * 64;     // float offset into T9
}

// ---- per-layer: G_slot = M_{slot+4} @ W^T (slot<8), W^T (slot 8); + bias ----
// 32 chunks per slot; each thread computes ONE fragment element (64-FMA dot).
// Fragment layout identical to verified k_mfrag: elem = G[(lane&31)+32t][16s+8hig+j]
__global__ __launch_bounds__(256)
void k_gfrag(const float* __restrict__ M, const float* __restrict__ W,
             const float* __restrict__ b, ushort* __restrict__ Ghi,
             ushort* __restrict__ Glo, float* __restrict__ bvec, const int F)
{
    __shared__ float Ml[4096];
    const int slot = blockIdx.x >> 5;
    const int chunk = blockIdx.x & 31;
    const int tid = threadIdx.x;
    const int KS = F >> 4;
    if (slot < 8) {
        const float* __restrict__ Mc = M + (slot + 4) * 4096;
        for (int i = tid; i < 4096; i += 256) Ml[i] = Mc[i];
    }
    __syncthreads();
    if (chunk == 0 && tid < 64) {
        float acc;
        if (slot < 8) {
            acc = 0.f;
            for (int e = 0; e < 64; ++e) acc += Ml[tid * 64 + e] * b[e];
        } else acc = b[tid];
        bvec[slot * 64 + tid] = acc;
    }
    const int total = 2 * KS * 512;          // t * s * lane * j
    const int per = (total + 31) >> 5;       // elems per chunk (256 or 128)
    const int uend = min((chunk + 1) * per, total);
    for (int u = chunk * per + tid; u < uend; u += 256) {
        const int j = u & 7;
        const int lane = (u >> 3) & 63;
        const int s = (u >> 9) % KS;
        const int t = u / (KS * 512);
        const int r = (lane & 31) + 32 * t;
        const int f = 16 * s + 8 * (lane >> 5) + j;
        float g;
        if (slot < 8) {
            g = 0.f;
            const float* __restrict__ wr = W + f * 64;
            const float* __restrict__ mr = Ml + r * 64;
#pragma unroll 16
            for (int e = 0; e < 64; ++e) g += mr[e] * wr[e];
        } else {
            g = W[f * 64 + r];
        }
        const int fid = ((slot * 2 + t) * KS + s) * 64 + lane;
        Ghi[fid * 8 + j] = bf_hi(g);
        Glo[fid * 8 + j] = bf_lo(g);
    }
}

// ---------------- act split: layer 0 (x direct) ----------------
__global__ __launch_bounds__(256)
void k_actx(const float* __restrict__ x, ushort* __restrict__ ahi,
            ushort* __restrict__ alo)
{
    const int t = blockIdx.x * 256 + threadIdx.x;
    if (t * 4 >= N_NODESC * 128) return;
    const float4 v = *(const float4*)&x[t * 4];
    ushort4 h4, l4;
    h4.x = bf_hi(v.x); h4.y = bf_hi(v.y); h4.z = bf_hi(v.z); h4.w = bf_hi(v.w);
    l4.x = bf_lo(v.x); l4.y = bf_lo(v.y); l4.z = bf_lo(v.z); l4.w = bf_lo(v.w);
    *(ushort4*)&ahi[t * 4] = h4;
    *(ushort4*)&alo[t * 4] = l4;
}

// ---------------- act: LN-apply + relu + split (layers 1,2) ----------------
__global__ __launch_bounds__(256)
void k_act(const float* __restrict__ outb, const float* __restrict__ scale,
           const float* __restrict__ shift, ushort* __restrict__ ahi,
           ushort* __restrict__ alo)
{
    const int t = blockIdx.x * 256 + threadIdx.x;
    if (t * 4 >= N_NODESC * 64) return;
    const int e0 = (t * 4) & 63;
    const float4 v = *(const float4*)&outb[t * 4];
    const float a0 = fmaxf(v.x * scale[e0] + shift[e0], 0.f);
    const float a1 = fmaxf(v.y * scale[e0 + 1] + shift[e0 + 1], 0.f);
    const float a2 = fmaxf(v.z * scale[e0 + 2] + shift[e0 + 2], 0.f);
    const float a3 = fmaxf(v.w * scale[e0 + 3] + shift[e0 + 3], 0.f);
    ushort4 h4, l4;
    h4.x = bf_hi(a0); h4.y = bf_hi(a1); h4.z = bf_hi(a2); h4.w = bf_hi(a3);
    l4.x = bf_lo(a0); l4.y = bf_lo(a1); l4.z = bf_lo(a2); l4.w = bf_lo(a3);
    *(ushort4*)&ahi[t * 4] = h4;
    *(ushort4*)&alo[t * 4] = l4;
}

// ---------------- 9-slot transform table (fused W + M GEMM) ----------------
// Block = 32 nodes; wave w handles slots w, w+4, (w==0: 8). C init = bias.
// Slot 8 output IS h (residual). Runtime KS keeps one B-set live (no spill).
__global__ __launch_bounds__(256, 3)
void k_T9(const ushort* __restrict__ ahi, const ushort* __restrict__ alo,
          const ushort* __restrict__ Ghi, const ushort* __restrict__ Glo,
          const float* __restrict__ bvec, float* __restrict__ T9,
          const int KS, const int F)
{
    __shared__ float msg[4][2048];        // per-wave 32 nodes x 64 feats (32 KB)
    const int tid = threadIdx.x;
    const int w = tid >> 6, lane = tid & 63;
    const int col = lane & 31, hig = lane >> 5;
    const int node = blockIdx.x * 32 + col;
    const ushort* __restrict__ rh = ahi + (long)node * F + hig * 8;
    const ushort* __restrict__ rl = alo + (long)node * F + hig * 8;
    float* __restrict__ msgw = msg[w];
    float* __restrict__ Tb = T9 + (long)blockIdx.x * 32 * TROW;

    for (int slot = w; slot < 9; slot += 4) {
        f32x16 c0, c1;
#pragma unroll
        for (int r = 0; r < 16; ++r) {
            const int fp = (r & 3) + 8 * (r >> 2) + 4 * hig;
            c0[r] = bvec[slot * 64 + fp];
            c1[r] = bvec[slot * 64 + fp + 32];
        }
        for (int s = 0; s < KS; ++s) {
            const int fid0 = ((slot * 2 + 0) * KS + s) * 64 + lane;
            const int fid1 = ((slot * 2 + 1) * KS + s) * 64 + lane;
            const short8 a0h = *(const short8*)&Ghi[fid0 * 8];
            const short8 a1h = *(const short8*)&Ghi[fid1 * 8];
            const short8 a0l = *(const short8*)&Glo[fid0 * 8];
            const short8 a1l = *(const short8*)&Glo[fid1 * 8];
            const short8 bh = *(const short8*)&rh[s * 16];
            const short8 bl = *(const short8*)&rl[s * 16];
            c0 = __builtin_amdgcn_mfma_f32_32x32x16_bf16(a0h, bh, c0, 0, 0, 0);
            c1 = __builtin_amdgcn_mfma_f32_32x32x16_bf16(a1h, bh, c1, 0, 0, 0);
            c0 = __builtin_amdgcn_mfma_f32_32x32x16_bf16(a0h, bl, c0, 0, 0, 0);
            c1 = __builtin_amdgcn_mfma_f32_32x32x16_bf16(a1h, bl, c1, 0, 0, 0);
            c0 = __builtin_amdgcn_mfma_f32_32x32x16_bf16(a0l, bh, c0, 0, 0, 0);
            c1 = __builtin_amdgcn_mfma_f32_32x32x16_bf16(a1l, bh, c1, 0, 0, 0);
        }

        // stage C tile to LDS (verified swizzle), then coalesced store-out
        const int sw = (col & 7) << 3;
        const int cb = col * 64;
#pragma unroll
        for (int rq = 0; rq < 4; ++rq) {
            const int fb = 8 * rq + 4 * hig;
            float4 v0 = {c0[4*rq], c0[4*rq+1], c0[4*rq+2], c0[4*rq+3]};
            float4 v1 = {c1[4*rq], c1[4*rq+1], c1[4*rq+2], c1[4*rq+3]};
            *(float4*)&msgw[cb + (fb ^ sw)] = v0;
            *(float4*)&msgw[cb + ((fb + 32) ^ sw)] = v1;
        }
        asm volatile("s_waitcnt lgkmcnt(0)" ::: "memory");
#pragma unroll
        for (int i = 0; i < 8; ++i) {
            const int idx = i * 64 + lane;
            const int row = idx >> 4, quad = idx & 15;
            const int qs = (row & 7) << 3;
            const float4 vv = *(const float4*)&msgw[row * 64 + ((quad * 4) ^ qs)];
            *(float4*)&Tb[(long)row * TROW + slot * 64 + quad * 4] = vv;
        }
        asm volatile("s_waitcnt lgkmcnt(0)" ::: "memory");
    }
}

// ---------------- gather-aggregate + residual(T9 slot 8) + LN partials ------
__global__ __launch_bounds__(256, 4)
void k_agg2(const float* __restrict__ T9, const int* __restrict__ elist,
            const int* __restrict__ seg, float* __restrict__ outb,
            float* __restrict__ pbuf)
{
    __shared__ float red[2][4][64];
    const int tid = threadIdx.x;
    const int w = tid >> 6, lane = tid & 63;
    const int dl = lane >> 2, fq = lane & 3;
    const int tile = blockIdx.x;
    const int gd = tile * 64 + w * 16 + dl;

    float4 a0 = {0,0,0,0}, a1 = a0, a2 = a0, a3 = a0;

    if (gd < N_NODESC) {
        const int p0 = seg[gd * 9];
        const int p1 = seg[gd * 9 + 9];
        const float* __restrict__ Tf = T9 + 16 * fq;
        int p = p0;
        for (; p + 4 <= p1; p += 4) {
            const long t0 = (long)elist[p];
            const long t1 = (long)elist[p + 1];
            const long t2 = (long)elist[p + 2];
            const long t3 = (long)elist[p + 3];
            const float4 u00 = *(const float4*)&Tf[t0 + 0];
            const float4 u01 = *(const float4*)&Tf[t0 + 4];
            const float4 u02 = *(const float4*)&Tf[t0 + 8];
            const float4 u03 = *(const float4*)&Tf[t0 + 12];
            const float4 u10 = *(const float4*)&Tf[t1 + 0];
            const float4 u11 = *(const float4*)&Tf[t1 + 4];
            const float4 u12 = *(const float4*)&Tf[t1 + 8];
            const float4 u13 = *(const float4*)&Tf[t1 + 12];
            const float4 u20 = *(const float4*)&Tf[t2 + 0];
            const float4 u21 = *(const float4*)&Tf[t2 + 4];
            const float4 u22 = *(const float4*)&Tf[t2 + 8];
            const float4 u23 = *(const float4*)&Tf[t2 + 12];
            const float4 u30 = *(const float4*)&Tf[t3 + 0];
            const float4 u31 = *(const float4*)&Tf[t3 + 4];
            const float4 u32 = *(const float4*)&Tf[t3 + 8];
            const float4 u33 = *(const float4*)&Tf[t3 + 12];
            a0.x += u00.x + u10.x + u20.x + u30.x;
            a0.y += u00.y + u10.y + u20.y + u30.y;
            a0.z += u00.z + u10.z + u20.z + u30.z;
            a0.w += u00.w + u10.w + u20.w + u30.w;
            a1.x += u01.x + u11.x + u21.x + u31.x;
            a1.y += u01.y + u11.y + u21.y + u31.y;
            a1.z += u01.z + u11.z + u21.z + u31.z;
            a1.w += u01.w + u11.w + u21.w + u31.w;
            a2.x += u02.x + u12.x + u22.x + u32.x;
            a2.y += u02.y + u12.y + u22.y + u32.y;
            a2.z += u02.z + u12.z + u22.z + u32.z;
            a2.w += u02.w + u12.w + u22.w + u32.w;
            a3.x += u03.x + u13.x + u23.x + u33.x;
            a3.y += u03.y + u13.y + u23.y + u33.y;
            a3.z += u03.z + u13.z + u23.z + u33.z;
            a3.w += u03.w + u13.w + u23.w + u33.w;
        }
        for (; p < p1; ++p) {
            const long t0 = (long)elist[p];
            const float4 u0 = *(const float4*)&Tf[t0 + 0];
            const float4 u1 = *(const float4*)&Tf[t0 + 4];
            const float4 u2 = *(const float4*)&Tf[t0 + 8];
            const float4 u3 = *(const float4*)&Tf[t0 + 12];
            a0.x += u0.x; a0.y += u0.y; a0.z += u0.z; a0.w += u0.w;
            a1.x += u1.x; a1.y += u1.y; a1.z += u1.z; a1.w += u1.w;
            a2.x += u2.x; a2.y += u2.y; a2.z += u2.z; a2.w += u2.w;
            a3.x += u3.x; a3.y += u3.y; a3.z += u3.z; a3.w += u3.w;
        }
    }

    // ---- epilogue: residual (T9 slot 8 = h) + store + LN partials ----
    float4 v[4] = {a0, a1, a2, a3};
    if (gd < N_NODESC) {
        const float4* __restrict__ hr =
            (const float4*)(T9 + (long)gd * TROW + 512 + 16 * fq);
        float4* __restrict__ ob = (float4*)(outb + (long)gd * 64 + 16 * fq);
#pragma unroll
        for (int u = 0; u < 4; ++u) {
            const float4 r = hr[u];
            v[u].x += r.x; v[u].y += r.y; v[u].z += r.z; v[u].w += r.w;
            ob[u] = v[u];
        }
    } else {
#pragma unroll
        for (int u = 0; u < 4; ++u) v[u] = make_float4(0.f, 0.f, 0.f, 0.f);
    }
    float s1[16], s2[16];
#pragma unroll
    for (int u = 0; u < 4; ++u) {
        s1[4*u+0] = v[u].x; s2[4*u+0] = v[u].x * v[u].x;
        s1[4*u+1] = v[u].y; s2[4*u+1] = v[u].y * v[u].y;
        s1[4*u+2] = v[u].z; s2[4*u+2] = v[u].z * v[u].z;
        s1[4*u+3] = v[u].w; s2[4*u+3] = v[u].w * v[u].w;
    }
#pragma unroll
    for (int j = 0; j < 16; ++j) {
        s1[j] += __shfl_xor(s1[j], 4);  s2[j] += __shfl_xor(s2[j], 4);
        s1[j] += __shfl_xor(s1[j], 8);  s2[j] += __shfl_xor(s2[j], 8);
        s1[j] += __shfl_xor(s1[j], 16); s2[j] += __shfl_xor(s2[j], 16);
        s1[j] += __shfl_xor(s1[j], 32); s2[j] += __shfl_xor(s2[j], 32);
    }
    if (dl == 0) {
#pragma unroll
        for (int j = 0; j < 16; ++j) {
            red[0][w][16 * fq + j] = s1[j];
            red[1][w][16 * fq + j] = s2[j];
        }
    }
    __syncthreads();
    if (tid < 64) {
        const float t1 = red[0][0][tid] + red[0][1][tid] + red[0][2][tid] + red[0][3][tid];
        const float t2 = red[1][0][tid] + red[1][1][tid] + red[1][2][tid] + red[1][3][tid];
        pbuf[tile * 128 + tid] = t1;
        pbuf[tile * 128 + 64 + tid] = t2;
    }
}

// ---------------- reduce LN partials -> scale/shift ----------------
__global__ __launch_bounds__(1024)
void k_norm2(const float* __restrict__ pbuf, const float* __restrict__ g,
             const float* __restrict__ be, float* __restrict__ scale,
             float* __restrict__ shift)
{
    __shared__ float s[1024];
    const int t = threadIdx.x, j = t & 127, gg = t >> 7;
    float a = 0.f;
    for (int b = gg; b < NTILE; b += 8) a += pbuf[b * 128 + j];
    s[t] = a;
    __syncthreads();
    if (t < 128) {
        float tot = 0.f;
#pragma unroll
        for (int k = 0; k < 8; ++k) tot += s[j + 128 * k];
        s[t] = tot;
    }
    __syncthreads();
    if (t < 64) {
        const double mu  = (double)s[t] / (double)N_NODESC;
        const double var = (double)s[64 + t] / (double)N_NODESC - mu * mu;
        const double sc  = (double)g[t] / sqrt(var + (double)EPSF);
        scale[t] = (float)sc;
        shift[t] = (float)((double)be[t] - mu * sc);
    }
}

// ---------------- final projection (LN apply fused) ----------------
__global__ __launch_bounds__(256)
void k_out(const float* __restrict__ outb, const float* __restrict__ scale,
           const float* __restrict__ shift, const float* __restrict__ resW,
           const float* __restrict__ resb, float* __restrict__ out)
{
    const int n = blockIdx.x * 256 + threadIdx.x;
    if (n >= N_NODESC) return;
    float a0 = resb[0], a1 = resb[1];
    const float* __restrict__ r = outb + (long)n * 64;
#pragma unroll 8
    for (int e = 0; e < 64; ++e) {
        const float v = fmaxf(r[e] * scale[e] + shift[e], 0.f);
        a0 += v * resW[2 * e];
        a1 += v * resW[2 * e + 1];
    }
    out[2 * n] = a0;
    out[2 * n + 1] = a1;
}

extern "C" void kernel_launch(void* const* d_in, const int* in_sizes, int n_in,
                              void* d_out, int out_size, void* d_ws, size_t ws_size,
                              hipStream_t stream)
{
    const float* x      = (const float*)d_in[0];
    const float* M      = (const float*)d_in[1];
    const int*   src    = (const int*)d_in[2];
    const int*   dst    = (const int*)d_in[3];
    const int*   labels = (const int*)d_in[4];
    const int*   bidx   = (const int*)d_in[5];
    const float* resW   = (const float*)d_in[18];
    const float* resb   = (const float*)d_in[19];
    float* out = (float*)d_out;

    char* ws = (char*)d_ws;
    float*  scale = (float*)(ws + WS_SCALE);
    float*  shift = (float*)(ws + WS_SHIFT);
    int*    bsum  = (int*)(ws + WS_BSUM);
    float*  pbuf  = (float*)(ws + WS_PBUF);
    int*    hist  = (int*)(ws + WS_HIST);
    int*    fill  = (int*)(ws + WS_FILL);
    int*    seg   = (int*)(ws + WS_SEG);
    int*    elist = (int*)(ws + WS_ELIST);
    ushort* Ghi   = (ushort*)(ws + WS_GHI);
    ushort* Glo   = (ushort*)(ws + WS_GLO);
    float*  bvec  = (float*)(ws + WS_BVEC);
    ushort* ahi   = (ushort*)(ws + WS_ACTHI);
    ushort* alo   = (ushort*)(ws + WS_ACTLO);
    float*  outb  = (float*)(ws + WS_OUTB);
    float*  T9    = (float*)(ws + WS_T9);

    // ---- preprocessing (graph constant across layers) ----
    hipMemsetAsync(hist, 0, 2 * (size_t)NKPAD9 * sizeof(int), stream);  // hist+fill
    k_hist9<<<NEBLK, 256, 0, stream>>>(src, dst, labels, bidx, hist);
    k_bsum<<<NHBLK9, 256, 0, stream>>>(hist, bsum);
    k_bscan2<<<1, 1024, 0, stream>>>(bsum);
    k_escan2<<<NHBLK9, 256, 0, stream>>>(hist, bsum, seg);
    k_scat9<<<NEBLK, 256, 0, stream>>>(src, dst, labels, bidx, seg, fill, elist);

    for (int l = 0; l < 3; ++l) {
        const float* W  = (const float*)d_in[6 + 4 * l];
        const float* b  = (const float*)d_in[7 + 4 * l];
        const float* g  = (const float*)d_in[8 + 4 * l];
        const float* be = (const float*)d_in[9 + 4 * l];
        const int F = (l == 0) ? 128 : 64;

        k_gfrag<<<9 * GCHUNK, 256, 0, stream>>>(M, W, b, Ghi, Glo, bvec, F);
        if (l == 0) {
            k_actx<<<6250, 256, 0, stream>>>(x, ahi, alo);
        } else {
            k_act<<<3125, 256, 0, stream>>>(outb, scale, shift, ahi, alo);
        }
        k_T9<<<NTBLK, 256, 0, stream>>>(ahi, alo, Ghi, Glo, bvec, T9, F >> 4, F);
        k_agg2<<<NTILE, 256, 0, stream>>>(T9, elist, seg, outb, pbuf);
        k_norm2<<<1, 1024, 0, stream>>>(pbuf, g, be, scale, shift);
    }
    k_out<<<(N_NODESC + 255) / 256, 256, 0, stream>>>(outb, scale, shift, resW, resb, out);
    (void)in_sizes; (void)n_in; (void)out_size; (void)ws_size;
}

// Round 20
// 403.128 us; speedup vs baseline: 2.6210x; 1.1497x over previous
//
#include <hip/hip_runtime.h>

// Problem constants
#define N_NODESC 50000
#define N_EDGESC 800000
#define EPSF 1e-5f
#define NTILE 782                   // ceil(50000/64)  (agg tiles)
#define NTBLK 1563                  // ceil(50000/32)  (k_T9 blocks)
#define TROW  576                   // 9*64 ushorts per T9b row
#define NKEY9 450000                // 50000*9
#define NKPAD9 450048               // 1758*256
#define NHBLK9 1758
#define NEBLK 3125                  // 800000/256
#define GCHUNK 32

typedef __attribute__((ext_vector_type(8))) short short8;
typedef __attribute__((ext_vector_type(8))) ushort ushort8;
typedef __attribute__((ext_vector_type(16))) float f32x16;

// ---- ws layout (bytes), total ~118 MB ----
#define WS_SCALE 0
#define WS_SHIFT 256
#define WS_BSUM  512                  // 1758 int
#define WS_PBUF  8704                 // 782*128 f32 -> ends 409088
#define WS_HIST  409600               // 450048 int
#define WS_FILL  2209792              // 450048 int
#define WS_SEG   4009984              // 450049 int -> pad
#define WS_ELIST 5810432              // 800000 int (ushort-offset into T9b)
#define WS_GHI   9010432              // 147456 B
#define WS_GLO   9157888              // 147456 B
#define WS_BVEC  9305344              // 9*64 f32 -> pad
#define WS_ACTHI 9308160              // 50016*128 ushort
#define WS_ACTLO 22112256             // 50016*128 ushort
#define WS_OUTB  34916352             // 50000*64 f32
#define WS_HRES  47716352             // 50016*64 f32 (residual, f32)
#define WS_T9B   60520448             // 50016*576 ushort = 57.6 MB

__device__ __forceinline__ ushort bf_hi(float v) {
    return (ushort)(__float_as_uint(v) >> 16);
}
__device__ __forceinline__ ushort bf_lo(float v) {
    const unsigned b = __float_as_uint(v);
    const float lof = v - __uint_as_float(b & 0xFFFF0000u);
    return (ushort)(__float_as_uint(lof) >> 16);
}
__device__ __forceinline__ ushort bf_rne(float v) {
    const unsigned b = __float_as_uint(v);
    return (ushort)((b + 0x7FFFu + ((b >> 16) & 1u)) >> 16);
}
__device__ __forceinline__ float bf_f(ushort u) {
    return __uint_as_float((unsigned)u << 16);
}

// slot: identity combos (label_dst==label_src) -> 8; else c-4 in [0,8)
__device__ __forceinline__ int edge_slot(int ld, int ls, int bx) {
    return (ld == ls) ? 8 : ((ld * 2 + ls) * 4 + bx - 4);
}

// ---------------- histogram over (dst, slot) ----------------
__global__ __launch_bounds__(256)
void k_hist9(const int* __restrict__ src, const int* __restrict__ dst,
             const int* __restrict__ labels, const int* __restrict__ bidx,
             int* __restrict__ hist)
{
    const int e = blockIdx.x * 256 + threadIdx.x;
    if (e >= N_EDGESC) return;
    const int s = src[e], d = dst[e];
    const int slot = edge_slot(labels[d], labels[s], bidx[e]);
    atomicAdd(&hist[d * 9 + slot], 1);
}

// ---------------- 3-level scan ----------------
__global__ __launch_bounds__(256)
void k_bsum(const int* __restrict__ hist, int* __restrict__ bsum)
{
    __shared__ int s[256];
    const int i = blockIdx.x * 256 + threadIdx.x;
    s[threadIdx.x] = hist[i];
    __syncthreads();
    for (int off = 128; off > 0; off >>= 1) {
        if (threadIdx.x < off) s[threadIdx.x] += s[threadIdx.x + off];
        __syncthreads();
    }
    if (threadIdx.x == 0) bsum[blockIdx.x] = s[0];
}

__global__ __launch_bounds__(1024)
void k_bscan2(int* __restrict__ bsum)
{
    __shared__ int s[1024];
    const int t = threadIdx.x;
    int v[4]; int tot = 0;
#pragma unroll
    for (int j = 0; j < 4; ++j) {
        const int i = t * 4 + j;
        v[j] = (i < NHBLK9) ? bsum[i] : 0;
        tot += v[j];
    }
    s[t] = tot; __syncthreads();
    for (int off = 1; off < 1024; off <<= 1) {
        const int x = (t >= off) ? s[t - off] : 0;
        __syncthreads();
        s[t] += x;
        __syncthreads();
    }
    int base = s[t] - tot;
#pragma unroll
    for (int j = 0; j < 4; ++j) {
        const int i = t * 4 + j;
        if (i < NHBLK9) bsum[i] = base;
        base += v[j];
    }
}

__global__ __launch_bounds__(256)
void k_escan2(const int* __restrict__ hist, const int* __restrict__ bsum,
              int* __restrict__ seg)
{
    __shared__ int s[256];
    const int t = threadIdx.x;
    const int i = blockIdx.x * 256 + t;
    const int v = hist[i];
    s[t] = v; __syncthreads();
    for (int off = 1; off < 256; off <<= 1) {
        const int x = (t >= off) ? s[t - off] : 0;
        __syncthreads();
        s[t] += x;
        __syncthreads();
    }
    seg[i] = bsum[blockIdx.x] + s[t] - v;
}

__global__ __launch_bounds__(256)
void k_scat9(const int* __restrict__ src, const int* __restrict__ dst,
             const int* __restrict__ labels, const int* __restrict__ bidx,
             const int* __restrict__ seg, int* __restrict__ fill,
             int* __restrict__ elist)
{
    const int e = blockIdx.x * 256 + threadIdx.x;
    if (e >= N_EDGESC) return;
    const int s = src[e], d = dst[e];
    const int slot = edge_slot(labels[d], labels[s], bidx[e]);
    const int k = d * 9 + slot;
    const int pos = seg[k] + atomicAdd(&fill[k], 1);
    elist[pos] = s * TROW + slot * 64;     // ushort offset into T9b
}

// ---- per-layer: G_slot = M_{slot+4} @ W^T (slot<8), W^T (slot 8); + bias ----
__global__ __launch_bounds__(256)
void k_gfrag(const float* __restrict__ M, const float* __restrict__ W,
             const float* __restrict__ b, ushort* __restrict__ Ghi,
             ushort* __restrict__ Glo, float* __restrict__ bvec, const int F)
{
    __shared__ float Ml[4096];
    const int slot = blockIdx.x >> 5;
    const int chunk = blockIdx.x & 31;
    const int tid = threadIdx.x;
    const int KS = F >> 4;
    if (slot < 8) {
        const float* __restrict__ Mc = M + (slot + 4) * 4096;
        for (int i = tid; i < 4096; i += 256) Ml[i] = Mc[i];
    }
    __syncthreads();
    if (chunk == 0 && tid < 64) {
        float acc;
        if (slot < 8) {
            acc = 0.f;
            for (int e = 0; e < 64; ++e) acc += Ml[tid * 64 + e] * b[e];
        } else acc = b[tid];
        bvec[slot * 64 + tid] = acc;
    }
    const int total = 2 * KS * 512;
    const int per = (total + 31) >> 5;
    const int uend = min((chunk + 1) * per, total);
    for (int u = chunk * per + tid; u < uend; u += 256) {
        const int j = u & 7;
        const int lane = (u >> 3) & 63;
        const int s = (u >> 9) % KS;
        const int t = u / (KS * 512);
        const int r = (lane & 31) + 32 * t;
        const int f = 16 * s + 8 * (lane >> 5) + j;
        float g;
        if (slot < 8) {
            g = 0.f;
            const float* __restrict__ wr = W + f * 64;
            const float* __restrict__ mr = Ml + r * 64;
#pragma unroll 16
            for (int e = 0; e < 64; ++e) g += mr[e] * wr[e];
        } else {
            g = W[f * 64 + r];
        }
        const int fid = ((slot * 2 + t) * KS + s) * 64 + lane;
        Ghi[fid * 8 + j] = bf_hi(g);
        Glo[fid * 8 + j] = bf_lo(g);
    }
}

// ---------------- act split: layer 0 (x direct) ----------------
__global__ __launch_bounds__(256)
void k_actx(const float* __restrict__ x, ushort* __restrict__ ahi,
            ushort* __restrict__ alo)
{
    const int t = blockIdx.x * 256 + threadIdx.x;
    if (t * 4 >= N_NODESC * 128) return;
    const float4 v = *(const float4*)&x[t * 4];
    ushort4 h4, l4;
    h4.x = bf_hi(v.x); h4.y = bf_hi(v.y); h4.z = bf_hi(v.z); h4.w = bf_hi(v.w);
    l4.x = bf_lo(v.x); l4.y = bf_lo(v.y); l4.z = bf_lo(v.z); l4.w = bf_lo(v.w);
    *(ushort4*)&ahi[t * 4] = h4;
    *(ushort4*)&alo[t * 4] = l4;
}

// ---------------- act: LN-apply + relu + split (layers 1,2) ----------------
__global__ __launch_bounds__(256)
void k_act(const float* __restrict__ outb, const float* __restrict__ scale,
           const float* __restrict__ shift, ushort* __restrict__ ahi,
           ushort* __restrict__ alo)
{
    const int t = blockIdx.x * 256 + threadIdx.x;
    if (t * 4 >= N_NODESC * 64) return;
    const int e0 = (t * 4) & 63;
    const float4 v = *(const float4*)&outb[t * 4];
    const float a0 = fmaxf(v.x * scale[e0] + shift[e0], 0.f);
    const float a1 = fmaxf(v.y * scale[e0 + 1] + shift[e0 + 1], 0.f);
    const float a2 = fmaxf(v.z * scale[e0 + 2] + shift[e0 + 2], 0.f);
    const float a3 = fmaxf(v.w * scale[e0 + 3] + shift[e0 + 3], 0.f);
    ushort4 h4, l4;
    h4.x = bf_hi(a0); h4.y = bf_hi(a1); h4.z = bf_hi(a2); h4.w = bf_hi(a3);
    l4.x = bf_lo(a0); l4.y = bf_lo(a1); l4.z = bf_lo(a2); l4.w = bf_lo(a3);
    *(ushort4*)&ahi[t * 4] = h4;
    *(ushort4*)&alo[t * 4] = l4;
}

// ---------------- 9-slot transform table -> bf16 T9b (+ f32 hres slot 8) ----
__global__ __launch_bounds__(256, 4)
void k_T9(const ushort* __restrict__ ahi, const ushort* __restrict__ alo,
          const ushort* __restrict__ Ghi, const ushort* __restrict__ Glo,
          const float* __restrict__ bvec, ushort* __restrict__ T9b,
          float* __restrict__ hres, const int KS, const int F)
{
    __shared__ float msg[4][2048];        // per-wave 32 nodes x 64 feats (32 KB)
    const int tid = threadIdx.x;
    const int w = tid >> 6, lane = tid & 63;
    const int col = lane & 31, hig = lane >> 5;
    const int node = blockIdx.x * 32 + col;
    const ushort* __restrict__ rh = ahi + (long)node * F + hig * 8;
    const ushort* __restrict__ rl = alo + (long)node * F + hig * 8;
    float* __restrict__ msgw = msg[w];
    ushort* __restrict__ Tb = T9b + (long)blockIdx.x * 32 * TROW;
    float* __restrict__ hb = hres + (long)blockIdx.x * 32 * 64;

    for (int slot = w; slot < 9; slot += 4) {
        f32x16 c0, c1;
#pragma unroll
        for (int r = 0; r < 16; ++r) {
            const int fp = (r & 3) + 8 * (r >> 2) + 4 * hig;
            c0[r] = bvec[slot * 64 + fp];
            c1[r] = bvec[slot * 64 + fp + 32];
        }
        for (int s = 0; s < KS; ++s) {
            const int fid0 = ((slot * 2 + 0) * KS + s) * 64 + lane;
            const int fid1 = ((slot * 2 + 1) * KS + s) * 64 + lane;
            const short8 a0h = *(const short8*)&Ghi[fid0 * 8];
            const short8 a1h = *(const short8*)&Ghi[fid1 * 8];
            const short8 a0l = *(const short8*)&Glo[fid0 * 8];
            const short8 a1l = *(const short8*)&Glo[fid1 * 8];
            const short8 bh = *(const short8*)&rh[s * 16];
            const short8 bl = *(const short8*)&rl[s * 16];
            c0 = __builtin_amdgcn_mfma_f32_32x32x16_bf16(a0h, bh, c0, 0, 0, 0);
            c1 = __builtin_amdgcn_mfma_f32_32x32x16_bf16(a1h, bh, c1, 0, 0, 0);
            c0 = __builtin_amdgcn_mfma_f32_32x32x16_bf16(a0h, bl, c0, 0, 0, 0);
            c1 = __builtin_amdgcn_mfma_f32_32x32x16_bf16(a1h, bl, c1, 0, 0, 0);
            c0 = __builtin_amdgcn_mfma_f32_32x32x16_bf16(a0l, bh, c0, 0, 0, 0);
            c1 = __builtin_amdgcn_mfma_f32_32x32x16_bf16(a1l, bh, c1, 0, 0, 0);
        }

        // stage C tile to LDS (verified swizzle)
        const int sw = (col & 7) << 3;
        const int cb = col * 64;
#pragma unroll
        for (int rq = 0; rq < 4; ++rq) {
            const int fb = 8 * rq + 4 * hig;
            float4 v0 = {c0[4*rq], c0[4*rq+1], c0[4*rq+2], c0[4*rq+3]};
            float4 v1 = {c1[4*rq], c1[4*rq+1], c1[4*rq+2], c1[4*rq+3]};
            *(float4*)&msgw[cb + (fb ^ sw)] = v0;
            *(float4*)&msgw[cb + ((fb + 32) ^ sw)] = v1;
        }
        asm volatile("s_waitcnt lgkmcnt(0)" ::: "memory");

        // bf16 store-out: 8 lanes cover one row's 128B (RNE)
#pragma unroll
        for (int i = 0; i < 4; ++i) {
            const int idx = i * 64 + lane;
            const int row = idx >> 3, oct = idx & 7;
            const int qs = (row & 7) << 3;
            const float4 va = *(const float4*)&msgw[row * 64 + ((oct * 8) ^ qs)];
            const float4 vb = *(const float4*)&msgw[row * 64 + ((oct * 8 + 4) ^ qs)];
            ushort8 u;
            u[0] = bf_rne(va.x); u[1] = bf_rne(va.y);
            u[2] = bf_rne(va.z); u[3] = bf_rne(va.w);
            u[4] = bf_rne(vb.x); u[5] = bf_rne(vb.y);
            u[6] = bf_rne(vb.z); u[7] = bf_rne(vb.w);
            *(ushort8*)&Tb[(long)row * TROW + slot * 64 + oct * 8] = u;
        }
        if (slot == 8) {      // residual also in f32
#pragma unroll
            for (int i = 0; i < 8; ++i) {
                const int idx = i * 64 + lane;
                const int row = idx >> 4, quad = idx & 15;
                const int qs = (row & 7) << 3;
                const float4 vv = *(const float4*)&msgw[row * 64 + ((quad * 4) ^ qs)];
                *(float4*)&hb[row * 64 + quad * 4] = vv;
            }
        }
        asm volatile("s_waitcnt lgkmcnt(0)" ::: "memory");
    }
}

// ---------------- gather-aggregate (bf16) + residual(f32) + LN partials -----
__global__ __launch_bounds__(256, 4)
void k_agg2(const ushort* __restrict__ T9b, const float* __restrict__ hres,
            const int* __restrict__ elist, const int* __restrict__ seg,
            float* __restrict__ outb, float* __restrict__ pbuf)
{
    __shared__ float red[2][4][64];
    const int tid = threadIdx.x;
    const int w = tid >> 6, lane = tid & 63;
    const int dl = lane >> 2, fq = lane & 3;
    const int tile = blockIdx.x;
    const int gd = tile * 64 + w * 16 + dl;

    float4 a0 = {0,0,0,0}, a1 = a0, a2 = a0, a3 = a0;

    if (gd < N_NODESC) {
        const int p0 = seg[gd * 9];
        const int p1 = seg[gd * 9 + 9];
        const ushort* __restrict__ Tf = T9b + 16 * fq;
        int p = p0;
        for (; p + 4 <= p1; p += 4) {
            const long t0 = (long)elist[p];
            const long t1 = (long)elist[p + 1];
            const long t2 = (long)elist[p + 2];
            const long t3 = (long)elist[p + 3];
            const ushort8 u0a = *(const ushort8*)&Tf[t0];
            const ushort8 u0b = *(const ushort8*)&Tf[t0 + 8];
            const ushort8 u1a = *(const ushort8*)&Tf[t1];
            const ushort8 u1b = *(const ushort8*)&Tf[t1 + 8];
            const ushort8 u2a = *(const ushort8*)&Tf[t2];
            const ushort8 u2b = *(const ushort8*)&Tf[t2 + 8];
            const ushort8 u3a = *(const ushort8*)&Tf[t3];
            const ushort8 u3b = *(const ushort8*)&Tf[t3 + 8];
#pragma unroll
            for (int k = 0; k < 4; ++k) {
                (&a0.x)[k] += bf_f(u0a[k]) + bf_f(u1a[k]) + bf_f(u2a[k]) + bf_f(u3a[k]);
                (&a1.x)[k] += bf_f(u0a[k+4]) + bf_f(u1a[k+4]) + bf_f(u2a[k+4]) + bf_f(u3a[k+4]);
                (&a2.x)[k] += bf_f(u0b[k]) + bf_f(u1b[k]) + bf_f(u2b[k]) + bf_f(u3b[k]);
                (&a3.x)[k] += bf_f(u0b[k+4]) + bf_f(u1b[k+4]) + bf_f(u2b[k+4]) + bf_f(u3b[k+4]);
            }
        }
        for (; p < p1; ++p) {
            const long t0 = (long)elist[p];
            const ushort8 ua = *(const ushort8*)&Tf[t0];
            const ushort8 ub = *(const ushort8*)&Tf[t0 + 8];
#pragma unroll
            for (int k = 0; k < 4; ++k) {
                (&a0.x)[k] += bf_f(ua[k]);
                (&a1.x)[k] += bf_f(ua[k+4]);
                (&a2.x)[k] += bf_f(ub[k]);
                (&a3.x)[k] += bf_f(ub[k+4]);
            }
        }
    }

    // ---- epilogue: residual (hres f32) + store + LN partials ----
    float4 v[4] = {a0, a1, a2, a3};
    if (gd < N_NODESC) {
        const float4* __restrict__ hr =
            (const float4*)(hres + (long)gd * 64 + 16 * fq);
        float4* __restrict__ ob = (float4*)(outb + (long)gd * 64 + 16 * fq);
#pragma unroll
        for (int u = 0; u < 4; ++u) {
            const float4 r = hr[u];
            v[u].x += r.x; v[u].y += r.y; v[u].z += r.z; v[u].w += r.w;
            ob[u] = v[u];
        }
    } else {
#pragma unroll
        for (int u = 0; u < 4; ++u) v[u] = make_float4(0.f, 0.f, 0.f, 0.f);
    }
    float s1[16], s2[16];
#pragma unroll
    for (int u = 0; u < 4; ++u) {
        s1[4*u+0] = v[u].x; s2[4*u+0] = v[u].x * v[u].x;
        s1[4*u+1] = v[u].y; s2[4*u+1] = v[u].y * v[u].y;
        s1[4*u+2] = v[u].z; s2[4*u+2] = v[u].z * v[u].z;
        s1[4*u+3] = v[u].w; s2[4*u+3] = v[u].w * v[u].w;
    }
#pragma unroll
    for (int j = 0; j < 16; ++j) {
        s1[j] += __shfl_xor(s1[j], 4);  s2[j] += __shfl_xor(s2[j], 4);
        s1[j] += __shfl_xor(s1[j], 8);  s2[j] += __shfl_xor(s2[j], 8);
        s1[j] += __shfl_xor(s1[j], 16); s2[j] += __shfl_xor(s2[j], 16);
        s1[j] += __shfl_xor(s1[j], 32); s2[j] += __shfl_xor(s2[j], 32);
    }
    if (dl == 0) {
#pragma unroll
        for (int j = 0; j < 16; ++j) {
            red[0][w][16 * fq + j] = s1[j];
            red[1][w][16 * fq + j] = s2[j];
        }
    }
    __syncthreads();
    if (tid < 64) {
        const float t1 = red[0][0][tid] + red[0][1][tid] + red[0][2][tid] + red[0][3][tid];
        const float t2 = red[1][0][tid] + red[1][1][tid] + red[1][2][tid] + red[1][3][tid];
        pbuf[tile * 128 + tid] = t1;
        pbuf[tile * 128 + 64 + tid] = t2;
    }
}

// ---------------- reduce LN partials -> scale/shift ----------------
__global__ __launch_bounds__(1024)
void k_norm2(const float* __restrict__ pbuf, const float* __restrict__ g,
             const float* __restrict__ be, float* __restrict__ scale,
             float* __restrict__ shift)
{
    __shared__ float s[1024];
    const int t = threadIdx.x, j = t & 127, gg = t >> 7;
    float a = 0.f;
    for (int b = gg; b < NTILE; b += 8) a += pbuf[b * 128 + j];
    s[t] = a;
    __syncthreads();
    if (t < 128) {
        float tot = 0.f;
#pragma unroll
        for (int k = 0; k < 8; ++k) tot += s[j + 128 * k];
        s[t] = tot;
    }
    __syncthreads();
    if (t < 64) {
        const double mu  = (double)s[t] / (double)N_NODESC;
        const double var = (double)s[64 + t] / (double)N_NODESC - mu * mu;
        const double sc  = (double)g[t] / sqrt(var + (double)EPSF);
        scale[t] = (float)sc;
        shift[t] = (float)((double)be[t] - mu * sc);
    }
}

// ---------------- final projection (LN apply fused) ----------------
__global__ __launch_bounds__(256)
void k_out(const float* __restrict__ outb, const float* __restrict__ scale,
           const float* __restrict__ shift, const float* __restrict__ resW,
           const float* __restrict__ resb, float* __restrict__ out)
{
    const int n = blockIdx.x * 256 + threadIdx.x;
    if (n >= N_NODESC) return;
    float a0 = resb[0], a1 = resb[1];
    const float* __restrict__ r = outb + (long)n * 64;
#pragma unroll 8
    for (int e = 0; e < 64; ++e) {
        const float v = fmaxf(r[e] * scale[e] + shift[e], 0.f);
        a0 += v * resW[2 * e];
        a1 += v * resW[2 * e + 1];
    }
    out[2 * n] = a0;
    out[2 * n + 1] = a1;
}

extern "C" void kernel_launch(void* const* d_in, const int* in_sizes, int n_in,
                              void* d_out, int out_size, void* d_ws, size_t ws_size,
                              hipStream_t stream)
{
    const float* x      = (const float*)d_in[0];
    const float* M      = (const float*)d_in[1];
    const int*   src    = (const int*)d_in[2];
    const int*   dst    = (const int*)d_in[3];
    const int*   labels = (const int*)d_in[4];
    const int*   bidx   = (const int*)d_in[5];
    const float* resW   = (const float*)d_in[18];
    const float* resb   = (const float*)d_in[19];
    float* out = (float*)d_out;

    char* ws = (char*)d_ws;
    float*  scale = (float*)(ws + WS_SCALE);
    float*  shift = (float*)(ws + WS_SHIFT);
    int*    bsum  = (int*)(ws + WS_BSUM);
    float*  pbuf  = (float*)(ws + WS_PBUF);
    int*    hist  = (int*)(ws + WS_HIST);
    int*    fill  = (int*)(ws + WS_FILL);
    int*    seg   = (int*)(ws + WS_SEG);
    int*    elist = (int*)(ws + WS_ELIST);
    ushort* Ghi   = (ushort*)(ws + WS_GHI);
    ushort* Glo   = (ushort*)(ws + WS_GLO);
    float*  bvec  = (float*)(ws + WS_BVEC);
    ushort* ahi   = (ushort*)(ws + WS_ACTHI);
    ushort* alo   = (ushort*)(ws + WS_ACTLO);
    float*  outb  = (float*)(ws + WS_OUTB);
    float*  hres  = (float*)(ws + WS_HRES);
    ushort* T9b   = (ushort*)(ws + WS_T9B);

    // ---- preprocessing (graph constant across layers) ----
    hipMemsetAsync(hist, 0, 2 * (size_t)NKPAD9 * sizeof(int), stream);  // hist+fill
    k_hist9<<<NEBLK, 256, 0, stream>>>(src, dst, labels, bidx, hist);
    k_bsum<<<NHBLK9, 256, 0, stream>>>(hist, bsum);
    k_bscan2<<<1, 1024, 0, stream>>>(bsum);
    k_escan2<<<NHBLK9, 256, 0, stream>>>(hist, bsum, seg);
    k_scat9<<<NEBLK, 256, 0, stream>>>(src, dst, labels, bidx, seg, fill, elist);

    for (int l = 0; l < 3; ++l) {
        const float* W  = (const float*)d_in[6 + 4 * l];
        const float* b  = (const float*)d_in[7 + 4 * l];
        const float* g  = (const float*)d_in[8 + 4 * l];
        const float* be = (const float*)d_in[9 + 4 * l];
        const int F = (l == 0) ? 128 : 64;

        k_gfrag<<<9 * GCHUNK, 256, 0, stream>>>(M, W, b, Ghi, Glo, bvec, F);
        if (l == 0) {
            k_actx<<<6250, 256, 0, stream>>>(x, ahi, alo);
        } else {
            k_act<<<3125, 256, 0, stream>>>(outb, scale, shift, ahi, alo);
        }
        k_T9<<<NTBLK, 256, 0, stream>>>(ahi, alo, Ghi, Glo, bvec, T9b, hres,
                                        F >> 4, F);
        k_agg2<<<NTILE, 256, 0, stream>>>(T9b, hres, elist, seg, outb, pbuf);
        k_norm2<<<1, 1024, 0, stream>>>(pbuf, g, be, scale, shift);
    }
    k_out<<<(N_NODESC + 255) / 256, 256, 0, stream>>>(outb, scale, shift, resW, resb, out);
    (void)in_sizes; (void)n_in; (void)out_size; (void)ws_size;
}